// Round 1
// baseline (11909.352 us; speedup 1.0000x reference)
//
#include <hip/hip_runtime.h>

#define B_    8
#define C_    96
#define H_    96
#define W_    96
#define HW_   (H_*W_)          // 9216
#define CHW_  (C_*HW_)         // 884736
#define BCHW_ 7077888          // 8*96*9216
#define OUTHALF_ 14155776      // 8*192*9216

// ---------------------------------------------------------------------------
// Generic 3x3 same-padding conv. Input is xa (channels 0..95) and optionally
// xb (channels 96..191, for the concat(x1,x2) case). Weights [Cout,Cin,3,3],
// optionally per-batch (wt_batch_stride != 0) for the attention-weighted conv.
// Grid: (36 tiles, 96 cout, 8 b), block 256 = 16x16 output pixels.
__global__ __launch_bounds__(256) void conv3x3_kernel(
    const float* __restrict__ xa, const float* __restrict__ xb,
    const float* __restrict__ wt, float* __restrict__ out,
    int cin, int wt_batch_stride)
{
    __shared__ float s_w[192*9];
    __shared__ float s_t[18][19];
    const int tid  = threadIdx.x;
    const int cout = blockIdx.y;
    const int b    = blockIdx.z;
    const int ty0  = (blockIdx.x / 6) * 16;
    const int tx0  = (blockIdx.x % 6) * 16;
    const int tyl  = tid >> 4, txl = tid & 15;

    const float* wp = wt + (size_t)b * wt_batch_stride + (size_t)cout * cin * 9;
    for (int i = tid; i < cin*9; i += 256) s_w[i] = wp[i];

    float acc = 0.f;
    for (int ci = 0; ci < cin; ++ci) {
        const float* src = (ci < C_) ? (xa + ((size_t)(b*C_ + ci))*HW_)
                                     : (xb + ((size_t)(b*C_ + ci - C_))*HW_);
        for (int i = tid; i < 18*18; i += 256) {
            int r = i / 18, c2 = i % 18;
            int gy = ty0 - 1 + r, gx = tx0 - 1 + c2;
            float v = 0.f;
            if ((unsigned)gy < (unsigned)H_ && (unsigned)gx < (unsigned)W_)
                v = src[gy*W_ + gx];
            s_t[r][c2] = v;
        }
        __syncthreads();
        const float* wr = &s_w[ci*9];
        acc += s_t[tyl+0][txl+0]*wr[0] + s_t[tyl+0][txl+1]*wr[1] + s_t[tyl+0][txl+2]*wr[2]
             + s_t[tyl+1][txl+0]*wr[3] + s_t[tyl+1][txl+1]*wr[4] + s_t[tyl+1][txl+2]*wr[5]
             + s_t[tyl+2][txl+0]*wr[6] + s_t[tyl+2][txl+1]*wr[7] + s_t[tyl+2][txl+2]*wr[8];
        __syncthreads();
    }
    out[((size_t)(b*C_ + cout))*HW_ + (size_t)(ty0+tyl)*W_ + (tx0+txl)] = acc;
}

// ---------------------------------------------------------------------------
// attn[b,p,ci,cj] = sum over the 1024 pixels (3*nh+kh, 3*nw+kw) of q[ci]*k[cj]
// Grid: (9 p, 8 b), block 256. LDS tiles over L in chunks of 64; row stride 65
// to avoid bank conflicts.
__global__ __launch_bounds__(256) void attn_logits_kernel(
    const float* __restrict__ q, const float* __restrict__ kk,
    float* __restrict__ attn)
{
    __shared__ float qs[96][65];
    __shared__ float ks[96][65];
    const int tid = threadIdx.x;
    const int p = blockIdx.x, b = blockIdx.y;
    const int kh = p / 3, kw = p % 3;

    float acc[36];
    int cis[36], cjs[36];
#pragma unroll
    for (int r = 0; r < 36; ++r) {
        int m = r*256 + tid;
        acc[r] = 0.f; cis[r] = m / 96; cjs[r] = m % 96;
    }

    for (int lt = 0; lt < 16; ++lt) {
        for (int i = tid; i < 96*64; i += 256) {
            int ci = i >> 6, l = i & 63;
            int gl = lt*64 + l;
            int y = 3*(gl >> 5) + kh, x = 3*(gl & 31) + kw;
            size_t off = ((size_t)(b*96 + ci))*HW_ + (size_t)y*W_ + x;
            qs[ci][l] = q[off];
            ks[ci][l] = kk[off];
        }
        __syncthreads();
#pragma unroll
        for (int r = 0; r < 36; ++r) {
            const float* qrow = qs[cis[r]];
            const float* krow = ks[cjs[r]];
            float a = acc[r];
#pragma unroll
            for (int l = 0; l < 64; ++l) a += qrow[l]*krow[l];
            acc[r] = a;
        }
        __syncthreads();
    }
    float* dst = attn + ((size_t)(b*9 + p))*9216;
#pragma unroll
    for (int r = 0; r < 36; ++r) dst[r*256 + tid] = acc[r];
}

// ---------------------------------------------------------------------------
// softmax over m = ci*9+p (864 entries) of attn[b,p,ci,cj]/sqrt(864),
// written as A[b,cj,m]. Grid: 768 = b*96+cj rows, block 256.
__global__ __launch_bounds__(256) void softmax_kernel(
    const float* __restrict__ attn, float* __restrict__ A)
{
    __shared__ float red[256];
    const int tid = threadIdx.x;
    const int cj = blockIdx.x % 96, b = blockIdx.x / 96;
    const float scale = 0.03402069087198858f;   // 1/sqrt(864)

    float v[4];
#pragma unroll
    for (int r = 0; r < 4; ++r) {
        int m = r*256 + tid;
        if (m < 864) {
            int ci = m / 9, pp = m % 9;
            v[r] = attn[(((size_t)(b*9 + pp))*96 + ci)*96 + cj] * scale;
        } else v[r] = -1e30f;
    }
    float mx = fmaxf(fmaxf(v[0], v[1]), fmaxf(v[2], v[3]));
    red[tid] = mx; __syncthreads();
    for (int s = 128; s > 0; s >>= 1) {
        if (tid < s) red[tid] = fmaxf(red[tid], red[tid+s]);
        __syncthreads();
    }
    mx = red[0]; __syncthreads();

    float e[4]; float lsum = 0.f;
#pragma unroll
    for (int r = 0; r < 4; ++r) {
        int m = r*256 + tid;
        if (m < 864) { e[r] = expf(v[r] - mx); lsum += e[r]; }
        else e[r] = 0.f;
    }
    red[tid] = lsum; __syncthreads();
    for (int s = 128; s > 0; s >>= 1) {
        if (tid < s) red[tid] += red[tid+s];
        __syncthreads();
    }
    float inv = 1.f / red[0];
#pragma unroll
    for (int r = 0; r < 4; ++r) {
        int m = r*256 + tid;
        if (m < 864) A[((size_t)(b*96 + cj))*864 + m] = e[r]*inv;
    }
}

// ---------------------------------------------------------------------------
// BN stats (training-mode, biased var) per channel for y1,y2,y3.
// Grid: 288 = t*96+c, block 256. stats[0..287]=mu, stats[288..575]=rstd.
__global__ __launch_bounds__(256) void bn_stats_kernel(
    const float* __restrict__ y1, const float* __restrict__ y2,
    const float* __restrict__ y3, float* __restrict__ stats)
{
    __shared__ float rs[256], rq[256];
    const int tid = threadIdx.x;
    const int t = blockIdx.x / 96, c = blockIdx.x % 96;
    const float* src = (t == 0) ? y1 : ((t == 1) ? y2 : y3);
    float s = 0.f, q2 = 0.f;
    for (int i = tid; i < B_*HW_; i += 256) {
        int b = i / HW_, hw = i % HW_;
        float val = src[((size_t)(b*96 + c))*HW_ + hw];
        s += val; q2 += val*val;
    }
    rs[tid] = s; rq[tid] = q2; __syncthreads();
    for (int st = 128; st > 0; st >>= 1) {
        if (tid < st) { rs[tid] += rs[tid+st]; rq[tid] += rq[tid+st]; }
        __syncthreads();
    }
    if (tid == 0) {
        const float n = (float)(B_*HW_);
        float mu = rs[0] / n;
        float var = rq[0] / n - mu*mu;
        stats[blockIdx.x] = mu;
        stats[288 + blockIdx.x] = rsqrtf(var + 1e-5f);
    }
}

// ---------------------------------------------------------------------------
// out0 = x + concat(bn(y1)*bn(y2), bn(y3)); out1 = x = concat(x1,x2).
__global__ __launch_bounds__(256) void final_kernel(
    const float* __restrict__ x1, const float* __restrict__ x2,
    const float* __restrict__ y1, const float* __restrict__ y2,
    const float* __restrict__ y3, const float* __restrict__ stats,
    float* __restrict__ out)
{
    size_t idx = (size_t)blockIdx.x*256 + threadIdx.x;   // < 7077888
    int b  = (int)(idx / CHW_);
    int c  = (int)((idx / HW_) % 96);
    int hw = (int)(idx % HW_);
    float mu1 = stats[c],      r1 = stats[288 + c];
    float mu2 = stats[96 + c], r2 = stats[288 + 96 + c];
    float mu3 = stats[192 + c], r3 = stats[288 + 192 + c];
    float x1v = x1[idx], x2v = x2[idx];
    float g  = ((y1[idx] - mu1)*r1) * ((y2[idx] - mu2)*r2);
    float n3 = (y3[idx] - mu3)*r3;
    size_t lo = ((size_t)(b*192 + c))*HW_ + hw;
    size_t hi = lo + (size_t)96*HW_;
    out[lo] = x1v + g;
    out[hi] = x2v + n3;
    out[OUTHALF_ + lo] = x1v;
    out[OUTHALF_ + hi] = x2v;
}

// ---------------------------------------------------------------------------
extern "C" void kernel_launch(void* const* d_in, const int* in_sizes, int n_in,
                              void* d_out, int out_size, void* d_ws, size_t ws_size,
                              hipStream_t stream)
{
    const float* x1  = (const float*)d_in[0];
    const float* x2  = (const float*)d_in[1];
    const float* w1  = (const float*)d_in[2];
    const float* w2  = (const float*)d_in[3];
    const float* wa1 = (const float*)d_in[4];
    const float* wa2 = (const float*)d_in[5];
    const float* wa3 = (const float*)d_in[6];
    float* out = (float*)d_out;
    float* ws  = (float*)d_ws;

    // ws layout (floats): y1, y2, y3 (3 * 7077888), attn (8*9*9216=663552),
    // A (8*96*864=663552), stats (576). Total ~86 MiB.
    float* y1   = ws;
    float* y2   = ws + (size_t)BCHW_;
    float* y3   = ws + 2*(size_t)BCHW_;
    float* attn = ws + 3*(size_t)BCHW_;
    float* A    = attn + (size_t)8*9*9216;
    float* stats= A + (size_t)8*96*864;

    // q,kk,v use d_out as scratch (dead before final_kernel writes d_out).
    float* q  = out;
    float* kk = out + (size_t)BCHW_;
    float* v  = out + 2*(size_t)BCHW_;

    dim3 cgrid(36, 96, 8);
    conv3x3_kernel<<<cgrid, 256, 0, stream>>>(x1, nullptr, w1, y1, 96, 0);
    conv3x3_kernel<<<cgrid, 256, 0, stream>>>(x2, nullptr, w2, y2, 96, 0);
    conv3x3_kernel<<<cgrid, 256, 0, stream>>>(x1, x2, wa1, q, 192, 0);
    conv3x3_kernel<<<cgrid, 256, 0, stream>>>(x1, x2, wa2, kk, 192, 0);
    conv3x3_kernel<<<cgrid, 256, 0, stream>>>(x1, x2, wa3, v, 192, 0);
    attn_logits_kernel<<<dim3(9, 8), 256, 0, stream>>>(q, kk, attn);
    softmax_kernel<<<768, 256, 0, stream>>>(attn, A);
    conv3x3_kernel<<<cgrid, 256, 0, stream>>>(v, nullptr, A, y3, 96, 96*864);
    bn_stats_kernel<<<288, 256, 0, stream>>>(y1, y2, y3, stats);
    final_kernel<<<27648, 256, 0, stream>>>(x1, x2, y1, y2, y3, stats, out);
}

// Round 2
// 620.012 us; speedup vs baseline: 19.2083x; 19.2083x over previous
//
#include <hip/hip_runtime.h>

#define B_    8
#define C_    96
#define H_    96
#define W_    96
#define HW_   9216
#define CHW_  884736
#define BCHW_ 7077888
#define OUTHALF_ 14155776
#define PAD_  98

typedef __attribute__((ext_vector_type(8))) short short8;
typedef __attribute__((ext_vector_type(4))) float f32x4;

__device__ __forceinline__ unsigned short f2bf(float f) {
    unsigned u = __builtin_bit_cast(unsigned, f);
    u = (u + 0x7FFFu + ((u >> 16) & 1u)) >> 16;
    return (unsigned short)u;
}
__device__ __forceinline__ float bf2f(unsigned short h) {
    return __builtin_bit_cast(float, (unsigned)h << 16);
}

__device__ __forceinline__ void gll16(const void* g, void* l) {
    __builtin_amdgcn_global_load_lds((const __attribute__((address_space(1))) void*)g,
                                     (__attribute__((address_space(3))) void*)l, 16, 0, 0);
}

// ---------------------------------------------------------------------------
// Pack concat(x1,x2) -> padded NHWC bf16 xb[8][98][98][192], zero border.
__global__ __launch_bounds__(256) void pack_x_kernel(
    const float* __restrict__ x1, const float* __restrict__ x2,
    unsigned short* __restrict__ xb)
{
    __shared__ unsigned short lds[192*100];
    const int tid = threadIdx.x;
    const int yp = blockIdx.x;      // 0..97
    const int b  = blockIdx.y;
    unsigned short* row = xb + ((size_t)(b*PAD_) + yp)*PAD_*192;
    if (yp == 0 || yp == PAD_-1) {
        for (int i = tid; i < PAD_*192; i += 256) row[i] = 0;
        return;
    }
    const int y = yp - 1;
    for (int i = tid; i < 2*HW_; i += 256) {
        const float* src = (i < HW_) ? x1 : x2;
        int ii = (i < HW_) ? i : i - HW_;
        int ch = ii / 96, x = ii - ch*96;
        int c = (i < HW_) ? ch : ch + 96;
        lds[c*100 + x] = f2bf(src[((size_t)(b*96 + ch))*HW_ + y*96 + x]);
    }
    __syncthreads();
    for (int i = tid; i < PAD_*192; i += 256) {
        int xp = i / 192, c = i - xp*192;
        row[i] = (xp == 0 || xp == PAD_-1) ? (unsigned short)0 : lds[c*100 + (xp-1)];
    }
}

// ---------------------------------------------------------------------------
// Pack conv weights fp32 [96][cin][3][3] -> bf16 fragment-linear layout:
// idx = (((step*6 + mf)*64 + lane)*8 + j), step = chunk*9 + tap,
// co = mf*16 + (lane&15), ci = chunk*32 + (lane>>4)*8 + j.
__global__ __launch_bounds__(256) void pack_w_kernel(
    const float* __restrict__ w, unsigned short* __restrict__ wf, int cin, int nelem)
{
    int i = blockIdx.x*256 + threadIdx.x;
    if (i >= nelem) return;
    int j = i & 7;
    int lane = (i >> 3) & 63;
    int blk = i >> 9;
    int mf = blk % 6;
    int step = blk / 6;
    int chunk = step / 9, tap = step - chunk*9;
    int kh = tap / 3, kw = tap - kh*3;
    int m = lane & 15, g = lane >> 4;
    int co = mf*16 + m;
    int ci = chunk*32 + g*8 + j;
    wf[i] = f2bf(w[(((size_t)co*cin + ci)*3 + kh)*3 + kw]);
}

// ---------------------------------------------------------------------------
// Implicit-GEMM 3x3 conv via MFMA. Input: padded NHWC bf16 (pixel stride
// CISTR channels). Weights: fragment-linear bf16 (per-batch stride wstride_b
// elems, 0 for shared). Block: 4 waves, tile M=96 cout x N=256 px (8r x 32c).
// MODE 0: fp32 NCHW out; 1: bf16 NCHW out; 2: bf16 padded-NHWC out (96 ch).
template<int CHUNKS, int CISTR, int MODE>
__global__ __launch_bounds__(256) void conv_mfma_kernel(
    const unsigned short* __restrict__ xin,
    const unsigned short* __restrict__ wf,
    int ci0_base, int wstride_b, void* __restrict__ outp)
{
    __shared__ __align__(16) unsigned short xs[352*32];   // [pos<=351][4 granules x 8]
    __shared__ __align__(16) unsigned short wsb[2][3072];
    const int tid  = threadIdx.x;
    const int lane = tid & 63;
    const int wid  = tid >> 6;
    const int wm   = wid & 1;     // cout half (48)
    const int wp   = wid >> 1;    // pixel-row half (4 rows)
    const int x0 = blockIdx.x*32, y0 = blockIdx.y*8, b = blockIdx.z;
    const int NSTEP = CHUNKS*9;
    const unsigned short* xbb = xin + (size_t)b*PAD_*PAD_*CISTR;
    const unsigned short* wfb = wf + (size_t)b*wstride_b;

    f32x4 acc[3][8];
    f32x4 zero = {0.f, 0.f, 0.f, 0.f};
#pragma unroll
    for (int a = 0; a < 3; ++a)
#pragma unroll
        for (int f = 0; f < 8; ++f) acc[a][f] = zero;

    for (int chunk = 0; chunk < CHUNKS; ++chunk) {
        // stage X chunk: rows y0..y0+9 (padded), cols x0..x0+33, 32 channels.
        {
            int ci0 = ci0_base + chunk*32;
            for (int r = wid; r < 22; r += 4) {
                int gi = r*64 + lane;
                int pos = gi >> 2; if (pos > 339) pos = 339;
                int g = gi & 3;
                int gsrc = (g ^ pos) & 3;               // XOR granule swizzle
                int ty = pos / 34, tx = pos - ty*34;
                const unsigned short* src = xbb
                    + ((size_t)(y0 + ty)*PAD_ + (x0 + tx))*CISTR + ci0 + gsrc*8;
                gll16(src, xs + r*512);
            }
        }
        if (chunk == 0) {
            for (int c = wid; c < 6; c += 4)
                gll16(wfb + c*512 + lane*8, wsb[0] + c*512);
        }
        __syncthreads();
        for (int tap = 0; tap < 9; ++tap) {
            int step = chunk*9 + tap;
            if (step + 1 < NSTEP) {   // prefetch next W into other half
                const unsigned short* wsrc = wfb + (size_t)(step+1)*3072;
                for (int c = wid; c < 6; c += 4)
                    gll16(wsrc + c*512 + lane*8, wsb[(step+1)&1] + c*512);
            }
            const unsigned short* wcur = wsb[step & 1];
            short8 a0 = *(const short8*)(wcur + ((wm*3+0)*64 + lane)*8);
            short8 a1 = *(const short8*)(wcur + ((wm*3+1)*64 + lane)*8);
            short8 a2 = *(const short8*)(wcur + ((wm*3+2)*64 + lane)*8);
            int kh = tap / 3, kw = tap - kh*3;
            int n = lane & 15, gw = lane >> 4;
#pragma unroll
            for (int r = 0; r < 4; ++r) {
#pragma unroll
                for (int xh = 0; xh < 2; ++xh) {
                    int pos = (wp*4 + r + kh)*34 + (xh*16 + n + kw);
                    int g = (gw ^ pos) & 3;
                    short8 bfrag = *(const short8*)(xs + pos*32 + g*8);
                    acc[0][r*2+xh] = __builtin_amdgcn_mfma_f32_16x16x32_bf16(a0, bfrag, acc[0][r*2+xh], 0, 0, 0);
                    acc[1][r*2+xh] = __builtin_amdgcn_mfma_f32_16x16x32_bf16(a1, bfrag, acc[1][r*2+xh], 0, 0, 0);
                    acc[2][r*2+xh] = __builtin_amdgcn_mfma_f32_16x16x32_bf16(a2, bfrag, acc[2][r*2+xh], 0, 0, 0);
                }
            }
            __syncthreads();
        }
    }
    // epilogue: C/D layout col=lane&15 (pixel), row=(lane>>4)*4+reg (cout).
    int n = lane & 15, gw = lane >> 4;
    if (MODE == 0) {
        float* out = (float*)outp;
#pragma unroll
        for (int a = 0; a < 3; ++a)
#pragma unroll
        for (int r = 0; r < 4; ++r)
#pragma unroll
        for (int xh = 0; xh < 2; ++xh) {
            int y = y0 + wp*4 + r, x = x0 + xh*16 + n;
#pragma unroll
            for (int reg = 0; reg < 4; ++reg) {
                int co = wm*48 + a*16 + gw*4 + reg;
                out[((size_t)(b*96 + co))*HW_ + y*96 + x] = acc[a][r*2+xh][reg];
            }
        }
    } else if (MODE == 1) {
        unsigned short* out = (unsigned short*)outp;
#pragma unroll
        for (int a = 0; a < 3; ++a)
#pragma unroll
        for (int r = 0; r < 4; ++r)
#pragma unroll
        for (int xh = 0; xh < 2; ++xh) {
            int y = y0 + wp*4 + r, x = x0 + xh*16 + n;
#pragma unroll
            for (int reg = 0; reg < 4; ++reg) {
                int co = wm*48 + a*16 + gw*4 + reg;
                out[((size_t)(b*96 + co))*HW_ + y*96 + x] = f2bf(acc[a][r*2+xh][reg]);
            }
        }
    } else {
        unsigned short* out = (unsigned short*)outp;  // padded NHWC, 96 ch
#pragma unroll
        for (int a = 0; a < 3; ++a)
#pragma unroll
        for (int r = 0; r < 4; ++r)
#pragma unroll
        for (int xh = 0; xh < 2; ++xh) {
            int y = y0 + wp*4 + r, x = x0 + xh*16 + n;
            int cb = wm*48 + a*16 + gw*4;
            f32x4 v = acc[a][r*2+xh];
            uint2 pv;
            pv.x = (unsigned)f2bf(v[0]) | ((unsigned)f2bf(v[1]) << 16);
            pv.y = (unsigned)f2bf(v[2]) | ((unsigned)f2bf(v[3]) << 16);
            *(uint2*)(out + ((size_t)(b*PAD_ + y+1)*PAD_ + (x+1))*96 + cb) = pv;
        }
    }
}

// ---------------------------------------------------------------------------
// attn logits via MFMA: per (b,tap): D[cq][ck] = sum_px q[cq,px]*k[ck,px],
// px over the 32x32 non-overlap grid (y=3i+kh, x=3j+kw). K-loop chunks of 32.
__global__ __launch_bounds__(256) void attn_mfma_kernel(
    const unsigned short* __restrict__ qb, const unsigned short* __restrict__ kb,
    float* __restrict__ attnb)
{
    __shared__ __align__(16) unsigned short qs[96*40];
    __shared__ __align__(16) unsigned short ks[96*40];
    const int tid = threadIdx.x, lane = tid & 63, wid = tid >> 6;
    const int tap = blockIdx.x, b = blockIdx.y;
    const int kh = tap / 3, kw = tap - kh*3;
    const int wm = wid & 1, wn = wid >> 1;
    f32x4 acc[3][3];
    f32x4 zero = {0.f, 0.f, 0.f, 0.f};
#pragma unroll
    for (int i = 0; i < 3; ++i)
#pragma unroll
        for (int j = 0; j < 3; ++j) acc[i][j] = zero;

    for (int i = 0; i < 32; ++i) {
        for (int t = tid; t < 3072; t += 256) {
            int cq = t >> 5, j = t & 31;
            size_t src = ((size_t)(b*96 + cq))*HW_ + (size_t)(3*i + kh)*96 + 3*j + kw;
            qs[cq*40 + j] = qb[src];
            ks[cq*40 + j] = kb[src];
        }
        __syncthreads();
        short8 av[3], bv[3];
#pragma unroll
        for (int am = 0; am < 3; ++am)
            av[am] = *(const short8*)(qs + (size_t)(wm*48 + am*16 + (lane&15))*40 + (lane>>4)*8);
#pragma unroll
        for (int bn = 0; bn < 3; ++bn)
            bv[bn] = *(const short8*)(ks + (size_t)(wn*48 + bn*16 + (lane&15))*40 + (lane>>4)*8);
#pragma unroll
        for (int am = 0; am < 3; ++am)
#pragma unroll
            for (int bn = 0; bn < 3; ++bn)
                acc[am][bn] = __builtin_amdgcn_mfma_f32_16x16x32_bf16(av[am], bv[bn], acc[am][bn], 0, 0, 0);
        __syncthreads();
    }
#pragma unroll
    for (int am = 0; am < 3; ++am)
#pragma unroll
    for (int bn = 0; bn < 3; ++bn)
#pragma unroll
    for (int reg = 0; reg < 4; ++reg) {
        int cq = wm*48 + am*16 + (lane>>4)*4 + reg;
        int ck = wn*48 + bn*16 + (lane&15);
        attnb[(((size_t)b*9 + tap)*96 + cq)*96 + ck] = acc[am][bn][reg];
    }
}

// ---------------------------------------------------------------------------
// softmax over m=(cq*9+tap) of attnb[b][tap][cq][ck]/sqrt(864); emits bf16
// per-batch conv weights in fragment-linear layout (co=ck, cin=cq).
__global__ __launch_bounds__(256) void softmax_kernel(
    const float* __restrict__ attnb, unsigned short* __restrict__ wfab)
{
    __shared__ float red[256];
    const int tid = threadIdx.x;
    const int ck = blockIdx.x % 96, b = blockIdx.x / 96;
    const float scale = 0.03402069087198858f;   // 1/sqrt(864)
    float v[4];
#pragma unroll
    for (int r = 0; r < 4; ++r) {
        int m = r*256 + tid;
        if (m < 864) {
            int cq = m / 9, tap = m - cq*9;
            v[r] = attnb[(((size_t)b*9 + tap)*96 + cq)*96 + ck] * scale;
        } else v[r] = -1e30f;
    }
    float mx = fmaxf(fmaxf(v[0], v[1]), fmaxf(v[2], v[3]));
    red[tid] = mx; __syncthreads();
    for (int s = 128; s > 0; s >>= 1) {
        if (tid < s) red[tid] = fmaxf(red[tid], red[tid+s]);
        __syncthreads();
    }
    mx = red[0]; __syncthreads();
    float e[4]; float lsum = 0.f;
#pragma unroll
    for (int r = 0; r < 4; ++r) {
        int m = r*256 + tid;
        if (m < 864) { e[r] = __expf(v[r] - mx); lsum += e[r]; }
        else e[r] = 0.f;
    }
    red[tid] = lsum; __syncthreads();
    for (int s = 128; s > 0; s >>= 1) {
        if (tid < s) red[tid] += red[tid+s];
        __syncthreads();
    }
    float inv = 1.f / red[0];
#pragma unroll
    for (int r = 0; r < 4; ++r) {
        int m = r*256 + tid;
        if (m < 864) {
            int cq = m / 9, tap = m - cq*9;
            int chunk = cq >> 5, cl = cq & 31, g = cl >> 3, j = cl & 7;
            int mf = ck >> 4, mrem = ck & 15;
            int lane2 = mrem + (g << 4);
            size_t oidx = (size_t)b*82944
                + ((((size_t)(chunk*9 + tap)*6 + mf)*64 + lane2)*8 + j);
            wfab[oidx] = f2bf(e[r]*inv);
        }
    }
}

// ---------------------------------------------------------------------------
__global__ __launch_bounds__(256) void bn_stats_kernel(
    const unsigned short* __restrict__ y1, const unsigned short* __restrict__ y2,
    const unsigned short* __restrict__ y3, float* __restrict__ stats)
{
    __shared__ float rs[256], rq[256];
    const int tid = threadIdx.x;
    const int t = blockIdx.x / 96, c = blockIdx.x % 96;
    const unsigned short* src = (t == 0) ? y1 : ((t == 1) ? y2 : y3);
    float s = 0.f, q2 = 0.f;
    for (int i = tid; i < 18432; i += 256) {   // 18432 quads = 8*9216/4
        int b = i / 2304, qd = i - b*2304;
        ushort4 v4 = *(const ushort4*)(src + ((size_t)(b*96 + c))*HW_ + qd*4);
        float f0 = bf2f(v4.x), f1 = bf2f(v4.y), f2v = bf2f(v4.z), f3 = bf2f(v4.w);
        s += f0+f1+f2v+f3; q2 += f0*f0+f1*f1+f2v*f2v+f3*f3;
    }
    rs[tid] = s; rq[tid] = q2; __syncthreads();
    for (int st = 128; st > 0; st >>= 1) {
        if (tid < st) { rs[tid] += rs[tid+st]; rq[tid] += rq[tid+st]; }
        __syncthreads();
    }
    if (tid == 0) {
        const float nn = 73728.f;
        float mu = rs[0] / nn;
        float var = rq[0] / nn - mu*mu;
        stats[blockIdx.x] = mu;
        stats[288 + blockIdx.x] = rsqrtf(var + 1e-5f);
    }
}

// ---------------------------------------------------------------------------
__global__ __launch_bounds__(256) void final_kernel(
    const float* __restrict__ x1, const float* __restrict__ x2,
    const unsigned short* __restrict__ y1, const unsigned short* __restrict__ y2,
    const unsigned short* __restrict__ y3, const float* __restrict__ stats,
    float* __restrict__ out)
{
    size_t q4 = (size_t)blockIdx.x*256 + threadIdx.x;  // quad id < 1769472
    size_t base = q4*4;
    int b  = (int)(base / CHW_);
    int c  = (int)((base / HW_) % 96);
    int hw = (int)(base % HW_);
    float mu1 = stats[c],       r1 = stats[288 + c];
    float mu2 = stats[96 + c],  r2 = stats[384 + c];
    float mu3 = stats[192 + c], r3 = stats[480 + c];
    float4 x1v = *(const float4*)(x1 + base);
    float4 x2v = *(const float4*)(x2 + base);
    ushort4 a1 = *(const ushort4*)(y1 + base);
    ushort4 a2 = *(const ushort4*)(y2 + base);
    ushort4 a3 = *(const ushort4*)(y3 + base);
    size_t lo = ((size_t)(b*192 + c))*HW_ + hw;
    size_t hi = lo + (size_t)96*HW_;
    float4 o0, o1;
    o0.x = x1v.x + ((bf2f(a1.x)-mu1)*r1) * ((bf2f(a2.x)-mu2)*r2);
    o0.y = x1v.y + ((bf2f(a1.y)-mu1)*r1) * ((bf2f(a2.y)-mu2)*r2);
    o0.z = x1v.z + ((bf2f(a1.z)-mu1)*r1) * ((bf2f(a2.z)-mu2)*r2);
    o0.w = x1v.w + ((bf2f(a1.w)-mu1)*r1) * ((bf2f(a2.w)-mu2)*r2);
    o1.x = x2v.x + (bf2f(a3.x)-mu3)*r3;
    o1.y = x2v.y + (bf2f(a3.y)-mu3)*r3;
    o1.z = x2v.z + (bf2f(a3.z)-mu3)*r3;
    o1.w = x2v.w + (bf2f(a3.w)-mu3)*r3;
    *(float4*)(out + lo) = o0;
    *(float4*)(out + hi) = o1;
    *(float4*)(out + OUTHALF_ + lo) = x1v;
    *(float4*)(out + OUTHALF_ + hi) = x2v;
}

// ---------------------------------------------------------------------------
extern "C" void kernel_launch(void* const* d_in, const int* in_sizes, int n_in,
                              void* d_out, int out_size, void* d_ws, size_t ws_size,
                              hipStream_t stream)
{
    const float* x1  = (const float*)d_in[0];
    const float* x2  = (const float*)d_in[1];
    const float* w1  = (const float*)d_in[2];
    const float* w2  = (const float*)d_in[3];
    const float* wa1 = (const float*)d_in[4];
    const float* wa2 = (const float*)d_in[5];
    const float* wa3 = (const float*)d_in[6];
    float* out = (float*)d_out;
    char* ws = (char*)d_ws;

    unsigned short* xb   = (unsigned short*)(ws);             // 29,503,488 B
    unsigned short* y1b  = (unsigned short*)(ws + 29503488);  // 14,155,776 B
    unsigned short* y2b  = (unsigned short*)(ws + 43659264);
    unsigned short* y3b  = (unsigned short*)(ws + 57815040);
    unsigned short* wf1  = (unsigned short*)(ws + 71970816);  // 165,888 B
    unsigned short* wf2  = (unsigned short*)(ws + 72136704);
    unsigned short* wfa1 = (unsigned short*)(ws + 72302592);  // 331,776 B
    unsigned short* wfa2 = (unsigned short*)(ws + 72634368);
    unsigned short* wfa3 = (unsigned short*)(ws + 72966144);
    unsigned short* wfab = (unsigned short*)(ws + 73297920);  // 1,327,104 B
    float* attnb = (float*)(ws + 74625024);                   // 2,654,208 B
    float* stats = (float*)(ws + 77279232);                   // 2,304 B

    // d_out scratch (all dead before final_kernel): q/k bf16 NCHW + v padded NHWC
    unsigned short* qb  = (unsigned short*)out;                          // 14,155,776 B
    unsigned short* kkb = (unsigned short*)((char*)out + 14155776);      // 14,155,776 B
    unsigned short* vb  = (unsigned short*)((char*)out + 28311552);      // 14,751,744 B

    pack_x_kernel<<<dim3(98, 8), 256, 0, stream>>>(x1, x2, xb);
    pack_w_kernel<<<324, 256, 0, stream>>>(w1, wf1, 96, 82944);
    pack_w_kernel<<<324, 256, 0, stream>>>(w2, wf2, 96, 82944);
    pack_w_kernel<<<648, 256, 0, stream>>>(wa1, wfa1, 192, 165888);
    pack_w_kernel<<<648, 256, 0, stream>>>(wa2, wfa2, 192, 165888);
    pack_w_kernel<<<648, 256, 0, stream>>>(wa3, wfa3, 192, 165888);
    hipMemsetAsync(vb, 0, (size_t)B_*PAD_*PAD_*96*2, stream);

    dim3 cgrid(3, 12, 8);
    conv_mfma_kernel<6,192,1><<<cgrid, 256, 0, stream>>>(xb, wfa1, 0, 0, qb);
    conv_mfma_kernel<6,192,1><<<cgrid, 256, 0, stream>>>(xb, wfa2, 0, 0, kkb);
    conv_mfma_kernel<6,192,2><<<cgrid, 256, 0, stream>>>(xb, wfa3, 0, 0, vb);
    conv_mfma_kernel<3,192,1><<<cgrid, 256, 0, stream>>>(xb, wf1, 0, 0, y1b);
    conv_mfma_kernel<3,192,1><<<cgrid, 256, 0, stream>>>(xb, wf2, 96, 0, y2b);
    attn_mfma_kernel<<<dim3(9, 8), 256, 0, stream>>>(qb, kkb, attnb);
    softmax_kernel<<<768, 256, 0, stream>>>(attnb, wfab);
    conv_mfma_kernel<3,96,1><<<cgrid, 256, 0, stream>>>(vb, wfab, 0, 82944, y3b);
    bn_stats_kernel<<<288, 256, 0, stream>>>(y1b, y2b, y3b, stats);
    final_kernel<<<6912, 256, 0, stream>>>(x1, x2, y1b, y2b, y3b, stats, out);
}

// Round 3
// 356.016 us; speedup vs baseline: 33.4517x; 1.7415x over previous
//
#include <hip/hip_runtime.h>

#define B_    8
#define C_    96
#define H_    96
#define W_    96
#define HW_   9216
#define CHW_  884736
#define BCHW_ 7077888
#define OUTHALF_ 14155776
#define PAD_  98

typedef __attribute__((ext_vector_type(8))) short short8;
typedef __attribute__((ext_vector_type(4))) float f32x4;

__device__ __forceinline__ unsigned short f2bf(float f) {
    unsigned u = __builtin_bit_cast(unsigned, f);
    u = (u + 0x7FFFu + ((u >> 16) & 1u)) >> 16;
    return (unsigned short)u;
}
__device__ __forceinline__ float bf2f(unsigned short h) {
    return __builtin_bit_cast(float, (unsigned)h << 16);
}

__device__ __forceinline__ void gll16(const void* g, void* l) {
    __builtin_amdgcn_global_load_lds((const __attribute__((address_space(1))) void*)g,
                                     (__attribute__((address_space(3))) void*)l, 16, 0, 0);
}

// ---------------------------------------------------------------------------
// Pack concat(x1,x2) -> padded NHWC bf16 xb[8][98][98][192], zero border.
__global__ __launch_bounds__(256) void pack_x_kernel(
    const float* __restrict__ x1, const float* __restrict__ x2,
    unsigned short* __restrict__ xb)
{
    __shared__ unsigned short lds[192*100];
    const int tid = threadIdx.x;
    const int yp = blockIdx.x;      // 0..97
    const int b  = blockIdx.y;
    unsigned short* row = xb + ((size_t)(b*PAD_) + yp)*PAD_*192;
    if (yp == 0 || yp == PAD_-1) {
        for (int i = tid; i < PAD_*192; i += 256) row[i] = 0;
        return;
    }
    const int y = yp - 1;
    for (int i = tid; i < 2*HW_; i += 256) {
        const float* src = (i < HW_) ? x1 : x2;
        int ii = (i < HW_) ? i : i - HW_;
        int ch = ii / 96, x = ii - ch*96;
        int c = (i < HW_) ? ch : ch + 96;
        lds[c*100 + x] = f2bf(src[((size_t)(b*96 + ch))*HW_ + y*96 + x]);
    }
    __syncthreads();
    for (int i = tid; i < PAD_*192; i += 256) {
        int xp = i / 192, c = i - xp*192;
        row[i] = (xp == 0 || xp == PAD_-1) ? (unsigned short)0 : lds[c*100 + (xp-1)];
    }
}

// ---------------------------------------------------------------------------
// Pack conv weights fp32 [96][cin][3][3] -> bf16 fragment-linear layout:
// idx = (((step*6 + mf)*64 + lane)*8 + j), step = chunk*9 + tap,
// co = mf*16 + (lane&15), ci = chunk*32 + (lane>>4)*8 + j.
__global__ __launch_bounds__(256) void pack_w_kernel(
    const float* __restrict__ w, unsigned short* __restrict__ wf, int cin, int nelem)
{
    int i = blockIdx.x*256 + threadIdx.x;
    if (i >= nelem) return;
    int j = i & 7;
    int lane = (i >> 3) & 63;
    int blk = i >> 9;
    int mf = blk % 6;
    int step = blk / 6;
    int chunk = step / 9, tap = step - chunk*9;
    int kh = tap / 3, kw = tap - kh*3;
    int m = lane & 15, g = lane >> 4;
    int co = mf*16 + m;
    int ci = chunk*32 + g*8 + j;
    wf[i] = f2bf(w[(((size_t)co*cin + ci)*3 + kh)*3 + kw]);
}

// ---------------------------------------------------------------------------
// Implicit-GEMM 3x3 conv via MFMA. X double-buffered in LDS (gll16-staged,
// XOR-granule swizzled), W loaded global->registers per tap (L2-resident).
// 2 barriers per 32-channel chunk; 216 MFMA per wave between barriers.
// MODE 0: fp32 NCHW out; 1: bf16 NCHW out; 2: bf16 padded-NHWC out (96 ch).
template<int CHUNKS, int CISTR, int MODE>
__global__ __launch_bounds__(256) void conv_mfma_kernel(
    const unsigned short* __restrict__ xin,
    const unsigned short* __restrict__ wf,
    int ci0_base, int wstride_b, void* __restrict__ outp)
{
    __shared__ __align__(16) unsigned short xs[2][352*32];
    const int tid  = threadIdx.x;
    const int lane = tid & 63;
    const int wid  = tid >> 6;
    const int wm   = wid & 1;     // cout half (48)
    const int wp   = wid >> 1;    // pixel-row half (4 rows)
    const int x0 = blockIdx.x*32, y0 = blockIdx.y*8, b = blockIdx.z;
    const unsigned short* xbb = xin + (size_t)b*PAD_*PAD_*CISTR;
    const unsigned short* wfb = wf + (size_t)b*wstride_b;

    auto stage = [&](int chunk, int buf) {
        int ci0 = ci0_base + chunk*32;
        for (int r = wid; r < 22; r += 4) {
            int gi = r*64 + lane;
            int pos = gi >> 2; if (pos > 339) pos = 339;
            int g = gi & 3;
            int gsrc = (g ^ pos) & 3;               // XOR granule swizzle
            int ty = pos / 34, tx = pos - ty*34;
            gll16(xbb + ((size_t)(y0 + ty)*PAD_ + (x0 + tx))*CISTR + ci0 + gsrc*8,
                  &xs[buf][r*512]);
        }
    };

    f32x4 acc[3][8];
    f32x4 zero = {0.f, 0.f, 0.f, 0.f};
#pragma unroll
    for (int a = 0; a < 3; ++a)
#pragma unroll
        for (int f = 0; f < 8; ++f) acc[a][f] = zero;

    stage(0, 0);
    for (int chunk = 0; chunk < CHUNKS; ++chunk) {
        const int cur = chunk & 1;
        if (chunk + 1 < CHUNKS) stage(chunk + 1, cur ^ 1);
        __syncthreads();
        const unsigned short* wchunk = wfb + (size_t)chunk*27648;
        for (int tap = 0; tap < 9; ++tap) {
            const unsigned short* wstep = wchunk + tap*3072;
            short8 a0 = *(const short8*)(wstep + ((wm*3+0)*64 + lane)*8);
            short8 a1 = *(const short8*)(wstep + ((wm*3+1)*64 + lane)*8);
            short8 a2 = *(const short8*)(wstep + ((wm*3+2)*64 + lane)*8);
            const int kh = tap / 3, kw = tap - kh*3;
            const int n = lane & 15, gw = lane >> 4;
#pragma unroll
            for (int r = 0; r < 4; ++r) {
#pragma unroll
                for (int xh = 0; xh < 2; ++xh) {
                    int pos = (wp*4 + r + kh)*34 + (xh*16 + n + kw);
                    int g = (gw ^ pos) & 3;
                    short8 bfrag = *(const short8*)(&xs[cur][pos*32 + g*8]);
                    acc[0][r*2+xh] = __builtin_amdgcn_mfma_f32_16x16x32_bf16(a0, bfrag, acc[0][r*2+xh], 0, 0, 0);
                    acc[1][r*2+xh] = __builtin_amdgcn_mfma_f32_16x16x32_bf16(a1, bfrag, acc[1][r*2+xh], 0, 0, 0);
                    acc[2][r*2+xh] = __builtin_amdgcn_mfma_f32_16x16x32_bf16(a2, bfrag, acc[2][r*2+xh], 0, 0, 0);
                }
            }
        }
        __syncthreads();
    }
    // epilogue: C/D layout col=lane&15 (pixel), row=(lane>>4)*4+reg (cout).
    int n = lane & 15, gw = lane >> 4;
    if (MODE == 0) {
        float* out = (float*)outp;
#pragma unroll
        for (int a = 0; a < 3; ++a)
#pragma unroll
        for (int r = 0; r < 4; ++r)
#pragma unroll
        for (int xh = 0; xh < 2; ++xh) {
            int y = y0 + wp*4 + r, x = x0 + xh*16 + n;
#pragma unroll
            for (int reg = 0; reg < 4; ++reg) {
                int co = wm*48 + a*16 + gw*4 + reg;
                out[((size_t)(b*96 + co))*HW_ + y*96 + x] = acc[a][r*2+xh][reg];
            }
        }
    } else if (MODE == 1) {
        unsigned short* out = (unsigned short*)outp;
#pragma unroll
        for (int a = 0; a < 3; ++a)
#pragma unroll
        for (int r = 0; r < 4; ++r)
#pragma unroll
        for (int xh = 0; xh < 2; ++xh) {
            int y = y0 + wp*4 + r, x = x0 + xh*16 + n;
#pragma unroll
            for (int reg = 0; reg < 4; ++reg) {
                int co = wm*48 + a*16 + gw*4 + reg;
                out[((size_t)(b*96 + co))*HW_ + y*96 + x] = f2bf(acc[a][r*2+xh][reg]);
            }
        }
    } else {
        unsigned short* out = (unsigned short*)outp;  // padded NHWC, 96 ch
#pragma unroll
        for (int a = 0; a < 3; ++a)
#pragma unroll
        for (int r = 0; r < 4; ++r)
#pragma unroll
        for (int xh = 0; xh < 2; ++xh) {
            int y = y0 + wp*4 + r, x = x0 + xh*16 + n;
            int cb = wm*48 + a*16 + gw*4;
            f32x4 v = acc[a][r*2+xh];
            uint2 pv;
            pv.x = (unsigned)f2bf(v[0]) | ((unsigned)f2bf(v[1]) << 16);
            pv.y = (unsigned)f2bf(v[2]) | ((unsigned)f2bf(v[3]) << 16);
            *(uint2*)(out + ((size_t)(b*PAD_ + y+1)*PAD_ + (x+1))*96 + cb) = pv;
        }
    }
}

// ---------------------------------------------------------------------------
// Repack q,k NCHW bf16 -> tap-major [b][tap(9)][ch(96)][L=1024] via LDS.
// Grid (96 ch, 8 b), block 256. Coalesced reads and writes.
__global__ __launch_bounds__(256) void repack_qk_kernel(
    const unsigned short* __restrict__ qb, const unsigned short* __restrict__ kb,
    unsigned short* __restrict__ qt, unsigned short* __restrict__ kt)
{
    __shared__ unsigned short q_lds[HW_], k_lds[HW_];
    const int tid = threadIdx.x;
    const int ch = blockIdx.x, b = blockIdx.y;
    const unsigned short* qsrc = qb + ((size_t)(b*96 + ch))*HW_;
    const unsigned short* ksrc = kb + ((size_t)(b*96 + ch))*HW_;
    for (int i = tid; i < HW_/8; i += 256) {
        *(short8*)(&q_lds[i*8]) = *(const short8*)(qsrc + i*8);
        *(short8*)(&k_lds[i*8]) = *(const short8*)(ksrc + i*8);
    }
    __syncthreads();
    const int l0 = tid*4;
    const int i0 = l0 >> 5, j0 = l0 & 31;
    for (int tap = 0; tap < 9; ++tap) {
        int kh = tap/3, kw = tap - kh*3;
        int base = (3*i0 + kh)*96 + kw;
        ushort4 vq, vk;
        vq.x = q_lds[base + 3*(j0+0)]; vq.y = q_lds[base + 3*(j0+1)];
        vq.z = q_lds[base + 3*(j0+2)]; vq.w = q_lds[base + 3*(j0+3)];
        vk.x = k_lds[base + 3*(j0+0)]; vk.y = k_lds[base + 3*(j0+1)];
        vk.z = k_lds[base + 3*(j0+2)]; vk.w = k_lds[base + 3*(j0+3)];
        size_t dst = (((size_t)(b*9 + tap))*96 + ch)*1024 + l0;
        *(ushort4*)(qt + dst) = vq;
        *(ushort4*)(kt + dst) = vk;
    }
}

// ---------------------------------------------------------------------------
// Gram partial: attnp[s][b][tap][cq][ck] = sum over L in [s*256,(s+1)*256) of
// qt[b][tap][cq][L]*kt[b][tap][ck][L]. Grid (9,8,4), block 256 (4 waves).
__global__ __launch_bounds__(256) void attn_mfma_kernel(
    const unsigned short* __restrict__ qt, const unsigned short* __restrict__ kt,
    float* __restrict__ attnp)
{
    __shared__ __align__(16) unsigned short qs[6144], ks[6144];
    const int tid = threadIdx.x, lane = tid & 63, wid = tid >> 6;
    const int tap = blockIdx.x, b = blockIdx.y, s = blockIdx.z;
    const int wm = wid & 1, wn = wid >> 1;
    const unsigned short* qbase = qt + ((size_t)(b*9 + tap))*96*1024;
    const unsigned short* kbase = kt + ((size_t)(b*9 + tap))*96*1024;

    f32x4 acc[3][3];
    f32x4 zero = {0.f, 0.f, 0.f, 0.f};
#pragma unroll
    for (int i = 0; i < 3; ++i)
#pragma unroll
        for (int j = 0; j < 3; ++j) acc[i][j] = zero;

    const int lrow = lane >> 3, lgr = lane & 7;
    for (int kc = 0; kc < 4; ++kc) {
        int L0 = s*256 + kc*64;
        for (int r = wid; r < 12; r += 4) {
            int row = r*8 + lrow;
            int gsrc = lgr ^ (row & 7);             // both-sides XOR swizzle
            gll16(qbase + (size_t)row*1024 + L0 + gsrc*8, &qs[r*512]);
        }
        for (int r = wid; r < 12; r += 4) {
            int row = r*8 + lrow;
            int gsrc = lgr ^ (row & 7);
            gll16(kbase + (size_t)row*1024 + L0 + gsrc*8, &ks[r*512]);
        }
        __syncthreads();
#pragma unroll
        for (int ks_ = 0; ks_ < 2; ++ks_) {
            short8 av[3], bv[3];
#pragma unroll
            for (int am = 0; am < 3; ++am) {
                int row = wm*48 + am*16 + (lane & 15);
                int gp = (ks_*4 + (lane >> 4)) ^ (row & 7);
                av[am] = *(const short8*)(&qs[row*64 + gp*8]);
            }
#pragma unroll
            for (int bn = 0; bn < 3; ++bn) {
                int row = wn*48 + bn*16 + (lane & 15);
                int gp = (ks_*4 + (lane >> 4)) ^ (row & 7);
                bv[bn] = *(const short8*)(&ks[row*64 + gp*8]);
            }
#pragma unroll
            for (int am = 0; am < 3; ++am)
#pragma unroll
                for (int bn = 0; bn < 3; ++bn)
                    acc[am][bn] = __builtin_amdgcn_mfma_f32_16x16x32_bf16(av[am], bv[bn], acc[am][bn], 0, 0, 0);
        }
        __syncthreads();
    }
    float* dst = attnp + ((((size_t)s*8 + b)*9 + tap))*9216;
#pragma unroll
    for (int am = 0; am < 3; ++am)
#pragma unroll
    for (int bn = 0; bn < 3; ++bn)
#pragma unroll
    for (int reg = 0; reg < 4; ++reg) {
        int cq = wm*48 + am*16 + (lane>>4)*4 + reg;
        int ck = wn*48 + bn*16 + (lane&15);
        dst[(size_t)cq*96 + ck] = acc[am][bn][reg];
    }
}

// ---------------------------------------------------------------------------
// softmax over m=(cq*9+tap) of sum_s attnp[s][b][tap][cq][ck]/sqrt(864);
// emits bf16 per-batch conv weights in fragment-linear layout (co=ck, cin=cq).
__global__ __launch_bounds__(256) void softmax_kernel(
    const float* __restrict__ attnp, unsigned short* __restrict__ wfab)
{
    __shared__ float red[256];
    const int tid = threadIdx.x;
    const int ck = blockIdx.x % 96, b = blockIdx.x / 96;
    const float scale = 0.03402069087198858f;   // 1/sqrt(864)
    float v[4];
#pragma unroll
    for (int r = 0; r < 4; ++r) {
        int m = r*256 + tid;
        if (m < 864) {
            int cq = m / 9, tap = m - cq*9;
            const float* ap = attnp + ((((size_t)b*9 + tap))*96 + cq)*96 + ck;
            v[r] = (ap[0] + ap[663552] + ap[2*663552] + ap[3*663552]) * scale;
        } else v[r] = -1e30f;
    }
    float mx = fmaxf(fmaxf(v[0], v[1]), fmaxf(v[2], v[3]));
    red[tid] = mx; __syncthreads();
    for (int s = 128; s > 0; s >>= 1) {
        if (tid < s) red[tid] = fmaxf(red[tid], red[tid+s]);
        __syncthreads();
    }
    mx = red[0]; __syncthreads();
    float e[4]; float lsum = 0.f;
#pragma unroll
    for (int r = 0; r < 4; ++r) {
        int m = r*256 + tid;
        if (m < 864) { e[r] = __expf(v[r] - mx); lsum += e[r]; }
        else e[r] = 0.f;
    }
    red[tid] = lsum; __syncthreads();
    for (int s = 128; s > 0; s >>= 1) {
        if (tid < s) red[tid] += red[tid+s];
        __syncthreads();
    }
    float inv = 1.f / red[0];
#pragma unroll
    for (int r = 0; r < 4; ++r) {
        int m = r*256 + tid;
        if (m < 864) {
            int cq = m / 9, tap = m - cq*9;
            int chunk = cq >> 5, cl = cq & 31, g = cl >> 3, j = cl & 7;
            int mf = ck >> 4, mrem = ck & 15;
            int lane2 = mrem + (g << 4);
            size_t oidx = (size_t)b*82944
                + ((((size_t)(chunk*9 + tap)*6 + mf)*64 + lane2)*8 + j);
            wfab[oidx] = f2bf(e[r]*inv);
        }
    }
}

// ---------------------------------------------------------------------------
__global__ __launch_bounds__(256) void bn_stats_kernel(
    const unsigned short* __restrict__ y1, const unsigned short* __restrict__ y2,
    const unsigned short* __restrict__ y3, float* __restrict__ stats)
{
    __shared__ float rs[256], rq[256];
    const int tid = threadIdx.x;
    const int t = blockIdx.x / 96, c = blockIdx.x % 96;
    const unsigned short* src = (t == 0) ? y1 : ((t == 1) ? y2 : y3);
    float s = 0.f, q2 = 0.f;
    for (int i = tid; i < 18432; i += 256) {
        int b = i / 2304, qd = i - b*2304;
        ushort4 v4 = *(const ushort4*)(src + ((size_t)(b*96 + c))*HW_ + qd*4);
        float f0 = bf2f(v4.x), f1 = bf2f(v4.y), f2v = bf2f(v4.z), f3 = bf2f(v4.w);
        s += f0+f1+f2v+f3; q2 += f0*f0+f1*f1+f2v*f2v+f3*f3;
    }
    rs[tid] = s; rq[tid] = q2; __syncthreads();
    for (int st = 128; st > 0; st >>= 1) {
        if (tid < st) { rs[tid] += rs[tid+st]; rq[tid] += rq[tid+st]; }
        __syncthreads();
    }
    if (tid == 0) {
        const float nn = 73728.f;
        float mu = rs[0] / nn;
        float var = rq[0] / nn - mu*mu;
        stats[blockIdx.x] = mu;
        stats[288 + blockIdx.x] = rsqrtf(var + 1e-5f);
    }
}

// ---------------------------------------------------------------------------
__global__ __launch_bounds__(256) void final_kernel(
    const float* __restrict__ x1, const float* __restrict__ x2,
    const unsigned short* __restrict__ y1, const unsigned short* __restrict__ y2,
    const unsigned short* __restrict__ y3, const float* __restrict__ stats,
    float* __restrict__ out)
{
    size_t q4 = (size_t)blockIdx.x*256 + threadIdx.x;  // quad id < 1769472
    size_t base = q4*4;
    int b  = (int)(base / CHW_);
    int c  = (int)((base / HW_) % 96);
    int hw = (int)(base % HW_);
    float mu1 = stats[c],       r1 = stats[288 + c];
    float mu2 = stats[96 + c],  r2 = stats[384 + c];
    float mu3 = stats[192 + c], r3 = stats[480 + c];
    float4 x1v = *(const float4*)(x1 + base);
    float4 x2v = *(const float4*)(x2 + base);
    ushort4 a1 = *(const ushort4*)(y1 + base);
    ushort4 a2 = *(const ushort4*)(y2 + base);
    ushort4 a3 = *(const ushort4*)(y3 + base);
    size_t lo = ((size_t)(b*192 + c))*HW_ + hw;
    size_t hi = lo + (size_t)96*HW_;
    float4 o0, o1;
    o0.x = x1v.x + ((bf2f(a1.x)-mu1)*r1) * ((bf2f(a2.x)-mu2)*r2);
    o0.y = x1v.y + ((bf2f(a1.y)-mu1)*r1) * ((bf2f(a2.y)-mu2)*r2);
    o0.z = x1v.z + ((bf2f(a1.z)-mu1)*r1) * ((bf2f(a2.z)-mu2)*r2);
    o0.w = x1v.w + ((bf2f(a1.w)-mu1)*r1) * ((bf2f(a2.w)-mu2)*r2);
    o1.x = x2v.x + (bf2f(a3.x)-mu3)*r3;
    o1.y = x2v.y + (bf2f(a3.y)-mu3)*r3;
    o1.z = x2v.z + (bf2f(a3.z)-mu3)*r3;
    o1.w = x2v.w + (bf2f(a3.w)-mu3)*r3;
    *(float4*)(out + lo) = o0;
    *(float4*)(out + hi) = o1;
    *(float4*)(out + OUTHALF_ + lo) = x1v;
    *(float4*)(out + OUTHALF_ + hi) = x2v;
}

// ---------------------------------------------------------------------------
extern "C" void kernel_launch(void* const* d_in, const int* in_sizes, int n_in,
                              void* d_out, int out_size, void* d_ws, size_t ws_size,
                              hipStream_t stream)
{
    const float* x1  = (const float*)d_in[0];
    const float* x2  = (const float*)d_in[1];
    const float* w1  = (const float*)d_in[2];
    const float* w2  = (const float*)d_in[3];
    const float* wa1 = (const float*)d_in[4];
    const float* wa2 = (const float*)d_in[5];
    const float* wa3 = (const float*)d_in[6];
    float* out = (float*)d_out;
    char* ws = (char*)d_ws;

    unsigned short* xb   = (unsigned short*)(ws);             // 29,503,488 B
    unsigned short* y1b  = (unsigned short*)(ws + 29503488);  // 14,155,776 B
    unsigned short* y2b  = (unsigned short*)(ws + 43659264);
    unsigned short* y3b  = (unsigned short*)(ws + 57815040);
    unsigned short* wf1  = (unsigned short*)(ws + 71970816);  // 165,888 B
    unsigned short* wf2  = (unsigned short*)(ws + 72136704);
    unsigned short* wfa1 = (unsigned short*)(ws + 72302592);  // 331,776 B
    unsigned short* wfa2 = (unsigned short*)(ws + 72634368);
    unsigned short* wfa3 = (unsigned short*)(ws + 72966144);
    unsigned short* wfab = (unsigned short*)(ws + 73297920);  // 1,327,104 B
    float* stats = (float*)(ws + 74625024);                   // 2,304 B

    // d_out scratch (all dead before final_kernel):
    unsigned short* qb    = (unsigned short*)out;                       // 14,155,776 B
    unsigned short* kkb   = (unsigned short*)((char*)out + 14155776);   // 14,155,776 B
    unsigned short* vb    = (unsigned short*)((char*)out + 28311552);   // 14,751,744 B
    unsigned short* qt    = (unsigned short*)((char*)out + 43063296);   // 14,155,776 B
    unsigned short* kt    = (unsigned short*)((char*)out + 57219072);   // 14,155,776 B
    float*          attnp = (float*)((char*)out + 71374848);            // 10,616,832 B

    pack_x_kernel<<<dim3(98, 8), 256, 0, stream>>>(x1, x2, xb);
    pack_w_kernel<<<324, 256, 0, stream>>>(w1, wf1, 96, 82944);
    pack_w_kernel<<<324, 256, 0, stream>>>(w2, wf2, 96, 82944);
    pack_w_kernel<<<648, 256, 0, stream>>>(wa1, wfa1, 192, 165888);
    pack_w_kernel<<<648, 256, 0, stream>>>(wa2, wfa2, 192, 165888);
    pack_w_kernel<<<648, 256, 0, stream>>>(wa3, wfa3, 192, 165888);
    hipMemsetAsync(vb, 0, (size_t)B_*PAD_*PAD_*96*2, stream);

    dim3 cgrid(3, 12, 8);
    conv_mfma_kernel<6,192,1><<<cgrid, 256, 0, stream>>>(xb, wfa1, 0, 0, qb);
    conv_mfma_kernel<6,192,1><<<cgrid, 256, 0, stream>>>(xb, wfa2, 0, 0, kkb);
    conv_mfma_kernel<6,192,2><<<cgrid, 256, 0, stream>>>(xb, wfa3, 0, 0, vb);
    conv_mfma_kernel<3,192,1><<<cgrid, 256, 0, stream>>>(xb, wf1, 0, 0, y1b);
    conv_mfma_kernel<3,192,1><<<cgrid, 256, 0, stream>>>(xb, wf2, 96, 0, y2b);
    repack_qk_kernel<<<dim3(96, 8), 256, 0, stream>>>(qb, kkb, qt, kt);
    attn_mfma_kernel<<<dim3(9, 8, 4), 256, 0, stream>>>(qt, kt, attnp);
    softmax_kernel<<<768, 256, 0, stream>>>(attnp, wfab);
    conv_mfma_kernel<3,96,1><<<cgrid, 256, 0, stream>>>(vb, wfab, 0, 82944, y3b);
    bn_stats_kernel<<<288, 256, 0, stream>>>(y1b, y2b, y3b, stats);
    final_kernel<<<6912, 256, 0, stream>>>(x1, x2, y1b, y2b, y3b, stats, out);
}

// Round 5
// 248.622 us; speedup vs baseline: 47.9015x; 1.4320x over previous
//
#include <hip/hip_runtime.h>

#define B_    8
#define C_    96
#define H_    96
#define W_    96
#define HW_   9216
#define CHW_  884736
#define BCHW_ 7077888
#define OUTHALF_ 14155776
#define PAD_  98

typedef __attribute__((ext_vector_type(8))) short short8;
typedef __attribute__((ext_vector_type(4))) float f32x4;

__device__ __forceinline__ unsigned short f2bf(float f) {
    unsigned u = __builtin_bit_cast(unsigned, f);
    u = (u + 0x7FFFu + ((u >> 16) & 1u)) >> 16;
    return (unsigned short)u;
}
__device__ __forceinline__ float bf2f(unsigned short h) {
    return __builtin_bit_cast(float, (unsigned)h << 16);
}

__device__ __forceinline__ void gll16(const void* g, void* l) {
    __builtin_amdgcn_global_load_lds((const __attribute__((address_space(1))) void*)g,
                                     (__attribute__((address_space(3))) void*)l, 16, 0, 0);
}

// ---------------------------------------------------------------------------
// Pack concat(x1,x2) -> padded NHWC bf16 xb[8][98][98][192], zero border.
// Extra grid row (yp==98): zero the border of vb (padded NHWC 96ch).
// NOTE: border zeroing must be exact — harness poisons buffers with 0xAA
// before timing; any unwritten-but-read cell fails replay validation.
__global__ __launch_bounds__(256) void pack_x_kernel(
    const float* __restrict__ x1, const float* __restrict__ x2,
    unsigned short* __restrict__ xb, unsigned short* __restrict__ vb)
{
    __shared__ unsigned short lds[192*100];
    const int tid = threadIdx.x;
    const int yp = blockIdx.x;      // 0..98
    const int b  = blockIdx.y;
    if (yp == 98) {                 // vb border zero for batch b
        unsigned short* vbb = vb + (size_t)b*PAD_*PAD_*96;
        for (int i = tid; i < 2*9408; i += 256) {   // rows 0 and 97 (full)
            int r = (i < 9408) ? 0 : 97;
            int o = (i < 9408) ? i : i - 9408;
            vbb[((size_t)r*PAD_)*96 + o] = 0;
        }
        for (int i = tid; i < 96*192; i += 256) {   // cols 0 and 97, rows 1..96
            int y = 1 + (i / 192);
            int rem = i % 192;
            int side = rem / 96;                    // 0 = col 0, 1 = col 97
            int c = rem % 96;
            vbb[((size_t)y*PAD_ + side*97)*96 + c] = 0;
        }
        return;
    }
    unsigned short* row = xb + ((size_t)(b*PAD_) + yp)*PAD_*192;
    if (yp == 0 || yp == PAD_-1) {
        for (int i = tid; i < PAD_*192; i += 256) row[i] = 0;
        return;
    }
    const int y = yp - 1;
    for (int i = tid; i < 2*HW_; i += 256) {
        const float* src = (i < HW_) ? x1 : x2;
        int ii = (i < HW_) ? i : i - HW_;
        int ch = ii / 96, x = ii - ch*96;
        int c = (i < HW_) ? ch : ch + 96;
        lds[c*100 + x] = f2bf(src[((size_t)(b*96 + ch))*HW_ + y*96 + x]);
    }
    __syncthreads();
    for (int i = tid; i < PAD_*192; i += 256) {
        int xp = i / 192, c = i - xp*192;
        row[i] = (xp == 0 || xp == PAD_-1) ? (unsigned short)0 : lds[c*100 + (xp-1)];
    }
}

// ---------------------------------------------------------------------------
// All 5 weight packs fused. fp32 [96][cin][3][3] -> bf16 fragment-linear:
// idx = (((step*6 + mf)*64 + lane)*8 + j), step = chunk*9 + tap,
// co = mf*16 + (lane&15), ci = chunk*32 + (lane>>4)*8 + j.
__global__ __launch_bounds__(256) void pack_w_all_kernel(
    const float* __restrict__ w1, const float* __restrict__ w2,
    const float* __restrict__ wa1, const float* __restrict__ wa2,
    const float* __restrict__ wa3,
    unsigned short* __restrict__ wf1, unsigned short* __restrict__ wf2,
    unsigned short* __restrict__ wfa1, unsigned short* __restrict__ wfa2,
    unsigned short* __restrict__ wfa3)
{
    int i = blockIdx.x*256 + threadIdx.x;   // < 663552
    const float* w; unsigned short* wf; int cin, rel;
    if      (i < 82944)  { w = w1;  wf = wf1;  cin = 96;  rel = i; }
    else if (i < 165888) { w = w2;  wf = wf2;  cin = 96;  rel = i - 82944; }
    else if (i < 331776) { w = wa1; wf = wfa1; cin = 192; rel = i - 165888; }
    else if (i < 497664) { w = wa2; wf = wfa2; cin = 192; rel = i - 331776; }
    else                 { w = wa3; wf = wfa3; cin = 192; rel = i - 497664; }
    int j = rel & 7;
    int lane = (rel >> 3) & 63;
    int blk = rel >> 9;
    int mf = blk % 6;
    int step = blk / 6;
    int chunk = step / 9, tap = step - chunk*9;
    int kh = tap / 3, kw = tap - kh*3;
    int m = lane & 15, g = lane >> 4;
    int co = mf*16 + m;
    int ci = chunk*32 + g*8 + j;
    wf[rel] = f2bf(w[(((size_t)co*cin + ci)*3 + kh)*3 + kw]);
}

// ---------------------------------------------------------------------------
// Fused implicit-GEMM 3x3 conv via MFMA, multi-job. blockIdx.z = which*8+b.
// T3 minimum 2-phase: issue stage(next) -> compute current -> ONE barrier.
// W loaded global->reg with next-tap prefetch. MODE 1: bf16 NCHW out;
// 2: bf16 padded-NHWC out (96 ch).
struct ConvJobs {
    const unsigned short* xin[5];
    const unsigned short* wf[5];
    unsigned short* out[5];
    int chunks[5];
    int ci0[5];
    int mode[5];
    int wstride[5];
    int cistr[5];
};

__global__ __launch_bounds__(256, 2) void conv_mfma_kernel(ConvJobs j)
{
    __shared__ __align__(16) unsigned short xs[2][352*32];
    const int tid  = threadIdx.x;
    const int lane = tid & 63;
    const int wid  = tid >> 6;
    const int wm   = wid & 1;     // cout half (48)
    const int wp   = wid >> 1;    // pixel-row half (4 rows)
    const int x0 = blockIdx.x*32, y0 = blockIdx.y*8;
    const int which = blockIdx.z >> 3, b = blockIdx.z & 7;
    const int CHUNKS = j.chunks[which];
    const int CISTR  = j.cistr[which];
    const int ci0_base = j.ci0[which];
    const int NSTEP = CHUNKS*9;
    const unsigned short* xbb = j.xin[which] + (size_t)b*PAD_*PAD_*CISTR;
    const unsigned short* wfb = j.wf[which] + (size_t)b*j.wstride[which];

    auto stage = [&](int chunk, int buf) {
        int ci0 = ci0_base + chunk*32;
        for (int r = wid; r < 22; r += 4) {
            int gi = r*64 + lane;
            int pos = gi >> 2; if (pos > 339) pos = 339;
            int g = gi & 3;
            int gsrc = (g ^ pos) & 3;               // XOR granule swizzle
            int ty = pos / 34, tx = pos - ty*34;
            gll16(xbb + ((size_t)(y0 + ty)*PAD_ + (x0 + tx))*CISTR + ci0 + gsrc*8,
                  &xs[buf][r*512]);
        }
    };
    auto loadW = [&](int step, short8& r0, short8& r1, short8& r2) {
        const unsigned short* wstep = wfb + (size_t)step*3072;
        r0 = *(const short8*)(wstep + ((wm*3+0)*64 + lane)*8);
        r1 = *(const short8*)(wstep + ((wm*3+1)*64 + lane)*8);
        r2 = *(const short8*)(wstep + ((wm*3+2)*64 + lane)*8);
    };

    f32x4 acc[3][8];
    f32x4 zero = {0.f, 0.f, 0.f, 0.f};
#pragma unroll
    for (int a = 0; a < 3; ++a)
#pragma unroll
        for (int f = 0; f < 8; ++f) acc[a][f] = zero;

    short8 wc0, wc1, wc2;
    loadW(0, wc0, wc1, wc2);
    stage(0, 0);
    __syncthreads();

    for (int chunk = 0; chunk < CHUNKS; ++chunk) {
        const int cur = chunk & 1;
        if (chunk + 1 < CHUNKS) stage(chunk + 1, cur ^ 1);   // issue; fly under MFMAs
        for (int tap = 0; tap < 9; ++tap) {
            const int step = chunk*9 + tap;
            const int nxt = (step + 1 < NSTEP) ? step + 1 : step;
            short8 wn0, wn1, wn2;
            loadW(nxt, wn0, wn1, wn2);                        // prefetch next tap
            const int kh = tap / 3, kw = tap - kh*3;
            const int n = lane & 15, gw = lane >> 4;
#pragma unroll
            for (int r = 0; r < 4; ++r) {
#pragma unroll
                for (int xh = 0; xh < 2; ++xh) {
                    int pos = (wp*4 + r + kh)*34 + (xh*16 + n + kw);
                    int g = (gw ^ pos) & 3;
                    short8 bfrag = *(const short8*)(&xs[cur][pos*32 + g*8]);
                    acc[0][r*2+xh] = __builtin_amdgcn_mfma_f32_16x16x32_bf16(wc0, bfrag, acc[0][r*2+xh], 0, 0, 0);
                    acc[1][r*2+xh] = __builtin_amdgcn_mfma_f32_16x16x32_bf16(wc1, bfrag, acc[1][r*2+xh], 0, 0, 0);
                    acc[2][r*2+xh] = __builtin_amdgcn_mfma_f32_16x16x32_bf16(wc2, bfrag, acc[2][r*2+xh], 0, 0, 0);
                }
            }
            wc0 = wn0; wc1 = wn1; wc2 = wn2;
        }
        __syncthreads();   // drains stage(next); protects xs[cur] reuse
    }

    // epilogue: C/D layout col=lane&15 (pixel), row=(lane>>4)*4+reg (cout).
    int n = lane & 15, gw = lane >> 4;
    if (j.mode[which] == 1) {
        unsigned short* out = j.out[which];
#pragma unroll
        for (int a = 0; a < 3; ++a)
#pragma unroll
        for (int r = 0; r < 4; ++r)
#pragma unroll
        for (int xh = 0; xh < 2; ++xh) {
            int y = y0 + wp*4 + r, x = x0 + xh*16 + n;
#pragma unroll
            for (int reg = 0; reg < 4; ++reg) {
                int co = wm*48 + a*16 + gw*4 + reg;
                out[((size_t)(b*96 + co))*HW_ + y*96 + x] = f2bf(acc[a][r*2+xh][reg]);
            }
        }
    } else {
        unsigned short* out = j.out[which];  // padded NHWC, 96 ch
#pragma unroll
        for (int a = 0; a < 3; ++a)
#pragma unroll
        for (int r = 0; r < 4; ++r)
#pragma unroll
        for (int xh = 0; xh < 2; ++xh) {
            int y = y0 + wp*4 + r, x = x0 + xh*16 + n;
            int cb = wm*48 + a*16 + gw*4;
            f32x4 v = acc[a][r*2+xh];
            uint2 pv;
            pv.x = (unsigned)f2bf(v[0]) | ((unsigned)f2bf(v[1]) << 16);
            pv.y = (unsigned)f2bf(v[2]) | ((unsigned)f2bf(v[3]) << 16);
            *(uint2*)(out + ((size_t)(b*PAD_ + y+1)*PAD_ + (x+1))*96 + cb) = pv;
        }
    }
}

// ---------------------------------------------------------------------------
// Repack q,k NCHW bf16 -> tap-major [b][tap(9)][ch(96)][L=1024] via LDS.
__global__ __launch_bounds__(256) void repack_qk_kernel(
    const unsigned short* __restrict__ qb, const unsigned short* __restrict__ kb,
    unsigned short* __restrict__ qt, unsigned short* __restrict__ kt)
{
    __shared__ unsigned short q_lds[HW_], k_lds[HW_];
    const int tid = threadIdx.x;
    const int ch = blockIdx.x, b = blockIdx.y;
    const unsigned short* qsrc = qb + ((size_t)(b*96 + ch))*HW_;
    const unsigned short* ksrc = kb + ((size_t)(b*96 + ch))*HW_;
    for (int i = tid; i < HW_/8; i += 256) {
        *(short8*)(&q_lds[i*8]) = *(const short8*)(qsrc + i*8);
        *(short8*)(&k_lds[i*8]) = *(const short8*)(ksrc + i*8);
    }
    __syncthreads();
    const int l0 = tid*4;
    const int i0 = l0 >> 5, j0 = l0 & 31;
    for (int tap = 0; tap < 9; ++tap) {
        int kh = tap/3, kw = tap - kh*3;
        int base = (3*i0 + kh)*96 + kw;
        ushort4 vq, vk;
        vq.x = q_lds[base + 3*(j0+0)]; vq.y = q_lds[base + 3*(j0+1)];
        vq.z = q_lds[base + 3*(j0+2)]; vq.w = q_lds[base + 3*(j0+3)];
        vk.x = k_lds[base + 3*(j0+0)]; vk.y = k_lds[base + 3*(j0+1)];
        vk.z = k_lds[base + 3*(j0+2)]; vk.w = k_lds[base + 3*(j0+3)];
        size_t dst = (((size_t)(b*9 + tap))*96 + ch)*1024 + l0;
        *(ushort4*)(qt + dst) = vq;
        *(ushort4*)(kt + dst) = vk;
    }
}

// ---------------------------------------------------------------------------
// Gram partial: attnp[s][b][tap][cq][ck], L-split s in 0..3.
__global__ __launch_bounds__(256) void attn_mfma_kernel(
    const unsigned short* __restrict__ qt, const unsigned short* __restrict__ kt,
    float* __restrict__ attnp)
{
    __shared__ __align__(16) unsigned short qs[6144], ks[6144];
    const int tid = threadIdx.x, lane = tid & 63, wid = tid >> 6;
    const int tap = blockIdx.x, b = blockIdx.y, s = blockIdx.z;
    const int wm = wid & 1, wn = wid >> 1;
    const unsigned short* qbase = qt + ((size_t)(b*9 + tap))*96*1024;
    const unsigned short* kbase = kt + ((size_t)(b*9 + tap))*96*1024;

    f32x4 acc[3][3];
    f32x4 zero = {0.f, 0.f, 0.f, 0.f};
#pragma unroll
    for (int i = 0; i < 3; ++i)
#pragma unroll
        for (int j = 0; j < 3; ++j) acc[i][j] = zero;

    const int lrow = lane >> 3, lgr = lane & 7;
    for (int kc = 0; kc < 4; ++kc) {
        int L0 = s*256 + kc*64;
        for (int r = wid; r < 12; r += 4) {
            int row = r*8 + lrow;
            int gsrc = lgr ^ (row & 7);             // both-sides XOR swizzle
            gll16(qbase + (size_t)row*1024 + L0 + gsrc*8, &qs[r*512]);
        }
        for (int r = wid; r < 12; r += 4) {
            int row = r*8 + lrow;
            int gsrc = lgr ^ (row & 7);
            gll16(kbase + (size_t)row*1024 + L0 + gsrc*8, &ks[r*512]);
        }
        __syncthreads();
#pragma unroll
        for (int ks_ = 0; ks_ < 2; ++ks_) {
            short8 av[3], bv[3];
#pragma unroll
            for (int am = 0; am < 3; ++am) {
                int row = wm*48 + am*16 + (lane & 15);
                int gp = (ks_*4 + (lane >> 4)) ^ (row & 7);
                av[am] = *(const short8*)(&qs[row*64 + gp*8]);
            }
#pragma unroll
            for (int bn = 0; bn < 3; ++bn) {
                int row = wn*48 + bn*16 + (lane & 15);
                int gp = (ks_*4 + (lane >> 4)) ^ (row & 7);
                bv[bn] = *(const short8*)(&ks[row*64 + gp*8]);
            }
#pragma unroll
            for (int am = 0; am < 3; ++am)
#pragma unroll
                for (int bn = 0; bn < 3; ++bn)
                    acc[am][bn] = __builtin_amdgcn_mfma_f32_16x16x32_bf16(av[am], bv[bn], acc[am][bn], 0, 0, 0);
        }
        __syncthreads();
    }
    float* dst = attnp + ((((size_t)s*8 + b)*9 + tap))*9216;
#pragma unroll
    for (int am = 0; am < 3; ++am)
#pragma unroll
    for (int bn = 0; bn < 3; ++bn)
#pragma unroll
    for (int reg = 0; reg < 4; ++reg) {
        int cq = wm*48 + am*16 + (lane>>4)*4 + reg;
        int ck = wn*48 + bn*16 + (lane&15);
        dst[(size_t)cq*96 + ck] = acc[am][bn][reg];
    }
}

// ---------------------------------------------------------------------------
// softmax over m=(cq*9+tap); emits bf16 per-batch conv weights fragment-linear.
__global__ __launch_bounds__(256) void softmax_kernel(
    const float* __restrict__ attnp, unsigned short* __restrict__ wfab)
{
    __shared__ float red[256];
    const int tid = threadIdx.x;
    const int ck = blockIdx.x % 96, b = blockIdx.x / 96;
    const float scale = 0.03402069087198858f;   // 1/sqrt(864)
    float v[4];
#pragma unroll
    for (int r = 0; r < 4; ++r) {
        int m = r*256 + tid;
        if (m < 864) {
            int cq = m / 9, tap = m - cq*9;
            const float* ap = attnp + ((((size_t)b*9 + tap))*96 + cq)*96 + ck;
            v[r] = (ap[0] + ap[663552] + ap[2*663552] + ap[3*663552]) * scale;
        } else v[r] = -1e30f;
    }
    float mx = fmaxf(fmaxf(v[0], v[1]), fmaxf(v[2], v[3]));
    red[tid] = mx; __syncthreads();
    for (int s = 128; s > 0; s >>= 1) {
        if (tid < s) red[tid] = fmaxf(red[tid], red[tid+s]);
        __syncthreads();
    }
    mx = red[0]; __syncthreads();
    float e[4]; float lsum = 0.f;
#pragma unroll
    for (int r = 0; r < 4; ++r) {
        int m = r*256 + tid;
        if (m < 864) { e[r] = __expf(v[r] - mx); lsum += e[r]; }
        else e[r] = 0.f;
    }
    red[tid] = lsum; __syncthreads();
    for (int s = 128; s > 0; s >>= 1) {
        if (tid < s) red[tid] += red[tid+s];
        __syncthreads();
    }
    float inv = 1.f / red[0];
#pragma unroll
    for (int r = 0; r < 4; ++r) {
        int m = r*256 + tid;
        if (m < 864) {
            int cq = m / 9, tap = m - cq*9;
            int chunk = cq >> 5, cl = cq & 31, g = cl >> 3, j = cl & 7;
            int mf = ck >> 4, mrem = ck & 15;
            int lane2 = mrem + (g << 4);
            size_t oidx = (size_t)b*82944
                + ((((size_t)(chunk*9 + tap)*6 + mf)*64 + lane2)*8 + j);
            wfab[oidx] = f2bf(e[r]*inv);
        }
    }
}

// ---------------------------------------------------------------------------
__global__ __launch_bounds__(256) void bn_stats_kernel(
    const unsigned short* __restrict__ y1, const unsigned short* __restrict__ y2,
    const unsigned short* __restrict__ y3, float* __restrict__ stats)
{
    __shared__ float rs[256], rq[256];
    const int tid = threadIdx.x;
    const int t = blockIdx.x / 96, c = blockIdx.x % 96;
    const unsigned short* src = (t == 0) ? y1 : ((t == 1) ? y2 : y3);
    float s = 0.f, q2 = 0.f;
    for (int i = tid; i < 18432; i += 256) {
        int b = i / 2304, qd = i - b*2304;
        ushort4 v4 = *(const ushort4*)(src + ((size_t)(b*96 + c))*HW_ + qd*4);
        float f0 = bf2f(v4.x), f1 = bf2f(v4.y), f2v = bf2f(v4.z), f3 = bf2f(v4.w);
        s += f0+f1+f2v+f3; q2 += f0*f0+f1*f1+f2v*f2v+f3*f3;
    }
    rs[tid] = s; rq[tid] = q2; __syncthreads();
    for (int st = 128; st > 0; st >>= 1) {
        if (tid < st) { rs[tid] += rs[tid+st]; rq[tid] += rq[tid+st]; }
        __syncthreads();
    }
    if (tid == 0) {
        const float nn = 73728.f;
        float mu = rs[0] / nn;
        float var = rq[0] / nn - mu*mu;
        stats[blockIdx.x] = mu;
        stats[288 + blockIdx.x] = rsqrtf(var + 1e-5f);
    }
}

// ---------------------------------------------------------------------------
__global__ __launch_bounds__(256) void final_kernel(
    const float* __restrict__ x1, const float* __restrict__ x2,
    const unsigned short* __restrict__ y1, const unsigned short* __restrict__ y2,
    const unsigned short* __restrict__ y3, const float* __restrict__ stats,
    float* __restrict__ out)
{
    size_t q4 = (size_t)blockIdx.x*256 + threadIdx.x;  // quad id < 1769472
    size_t base = q4*4;
    int b  = (int)(base / CHW_);
    int c  = (int)((base / HW_) % 96);
    int hw = (int)(base % HW_);
    float mu1 = stats[c],       r1 = stats[288 + c];
    float mu2 = stats[96 + c],  r2 = stats[384 + c];
    float mu3 = stats[192 + c], r3 = stats[480 + c];
    float4 x1v = *(const float4*)(x1 + base);
    float4 x2v = *(const float4*)(x2 + base);
    ushort4 a1 = *(const ushort4*)(y1 + base);
    ushort4 a2 = *(const ushort4*)(y2 + base);
    ushort4 a3 = *(const ushort4*)(y3 + base);
    size_t lo = ((size_t)(b*192 + c))*HW_ + hw;
    size_t hi = lo + (size_t)96*HW_;
    float4 o0, o1;
    o0.x = x1v.x + ((bf2f(a1.x)-mu1)*r1) * ((bf2f(a2.x)-mu2)*r2);
    o0.y = x1v.y + ((bf2f(a1.y)-mu1)*r1) * ((bf2f(a2.y)-mu2)*r2);
    o0.z = x1v.z + ((bf2f(a1.z)-mu1)*r1) * ((bf2f(a2.z)-mu2)*r2);
    o0.w = x1v.w + ((bf2f(a1.w)-mu1)*r1) * ((bf2f(a2.w)-mu2)*r2);
    o1.x = x2v.x + (bf2f(a3.x)-mu3)*r3;
    o1.y = x2v.y + (bf2f(a3.y)-mu3)*r3;
    o1.z = x2v.z + (bf2f(a3.z)-mu3)*r3;
    o1.w = x2v.w + (bf2f(a3.w)-mu3)*r3;
    *(float4*)(out + lo) = o0;
    *(float4*)(out + hi) = o1;
    *(float4*)(out + OUTHALF_ + lo) = x1v;
    *(float4*)(out + OUTHALF_ + hi) = x2v;
}

// ---------------------------------------------------------------------------
extern "C" void kernel_launch(void* const* d_in, const int* in_sizes, int n_in,
                              void* d_out, int out_size, void* d_ws, size_t ws_size,
                              hipStream_t stream)
{
    const float* x1  = (const float*)d_in[0];
    const float* x2  = (const float*)d_in[1];
    const float* w1  = (const float*)d_in[2];
    const float* w2  = (const float*)d_in[3];
    const float* wa1 = (const float*)d_in[4];
    const float* wa2 = (const float*)d_in[5];
    const float* wa3 = (const float*)d_in[6];
    float* out = (float*)d_out;
    char* ws = (char*)d_ws;

    unsigned short* xb   = (unsigned short*)(ws);             // 29,503,488 B
    unsigned short* y1b  = (unsigned short*)(ws + 29503488);  // 14,155,776 B
    unsigned short* y2b  = (unsigned short*)(ws + 43659264);
    unsigned short* y3b  = (unsigned short*)(ws + 57815040);
    unsigned short* wf1  = (unsigned short*)(ws + 71970816);  // 165,888 B
    unsigned short* wf2  = (unsigned short*)(ws + 72136704);
    unsigned short* wfa1 = (unsigned short*)(ws + 72302592);  // 331,776 B
    unsigned short* wfa2 = (unsigned short*)(ws + 72634368);
    unsigned short* wfa3 = (unsigned short*)(ws + 72966144);
    unsigned short* wfab = (unsigned short*)(ws + 73297920);  // 1,327,104 B
    float* stats = (float*)(ws + 74625024);                   // 2,304 B

    // d_out scratch (all dead before final_kernel):
    unsigned short* qb    = (unsigned short*)out;                       // 14,155,776 B
    unsigned short* kkb   = (unsigned short*)((char*)out + 14155776);   // 14,155,776 B
    unsigned short* vb    = (unsigned short*)((char*)out + 28311552);   // 14,751,744 B
    unsigned short* qt    = (unsigned short*)((char*)out + 43063296);   // 14,155,776 B
    unsigned short* kt    = (unsigned short*)((char*)out + 57219072);   // 14,155,776 B
    float*          attnp = (float*)((char*)out + 71374848);            // 10,616,832 B

    pack_w_all_kernel<<<2592, 256, 0, stream>>>(w1, w2, wa1, wa2, wa3,
                                                wf1, wf2, wfa1, wfa2, wfa3);
    pack_x_kernel<<<dim3(99, 8), 256, 0, stream>>>(x1, x2, xb, vb);

    ConvJobs jA;
    jA.xin[0]=xb;  jA.wf[0]=wfa1; jA.out[0]=qb;  jA.chunks[0]=6; jA.ci0[0]=0;  jA.mode[0]=1; jA.wstride[0]=0; jA.cistr[0]=192;
    jA.xin[1]=xb;  jA.wf[1]=wfa2; jA.out[1]=kkb; jA.chunks[1]=6; jA.ci0[1]=0;  jA.mode[1]=1; jA.wstride[1]=0; jA.cistr[1]=192;
    jA.xin[2]=xb;  jA.wf[2]=wfa3; jA.out[2]=vb;  jA.chunks[2]=6; jA.ci0[2]=0;  jA.mode[2]=2; jA.wstride[2]=0; jA.cistr[2]=192;
    jA.xin[3]=xb;  jA.wf[3]=wf1;  jA.out[3]=y1b; jA.chunks[3]=3; jA.ci0[3]=0;  jA.mode[3]=1; jA.wstride[3]=0; jA.cistr[3]=192;
    jA.xin[4]=xb;  jA.wf[4]=wf2;  jA.out[4]=y2b; jA.chunks[4]=3; jA.ci0[4]=96; jA.mode[4]=1; jA.wstride[4]=0; jA.cistr[4]=192;
    conv_mfma_kernel<<<dim3(3, 12, 40), 256, 0, stream>>>(jA);

    repack_qk_kernel<<<dim3(96, 8), 256, 0, stream>>>(qb, kkb, qt, kt);
    attn_mfma_kernel<<<dim3(9, 8, 4), 256, 0, stream>>>(qt, kt, attnp);
    softmax_kernel<<<768, 256, 0, stream>>>(attnp, wfab);

    ConvJobs jB;
    for (int s = 0; s < 5; ++s) {
        jB.xin[s]=vb; jB.wf[s]=wfab; jB.out[s]=y3b; jB.chunks[s]=3; jB.ci0[s]=0;
        jB.mode[s]=1; jB.wstride[s]=82944; jB.cistr[s]=96;
    }
    conv_mfma_kernel<<<dim3(3, 12, 8), 256, 0, stream>>>(jB);

    bn_stats_kernel<<<288, 256, 0, stream>>>(y1b, y2b, y3b, stats);
    final_kernel<<<6912, 256, 0, stream>>>(x1, x2, y1b, y2b, y3b, stats, out);
}

// Round 6
// 237.412 us; speedup vs baseline: 50.1631x; 1.0472x over previous
//
#include <hip/hip_runtime.h>

#define B_    8
#define C_    96
#define H_    96
#define W_    96
#define HW_   9216
#define CHW_  884736
#define BCHW_ 7077888
#define OUTHALF_ 14155776
#define PAD_  98

typedef __attribute__((ext_vector_type(8))) short short8;
typedef __attribute__((ext_vector_type(4))) float f32x4;

__device__ __forceinline__ unsigned short f2bf(float f) {
    unsigned u = __builtin_bit_cast(unsigned, f);
    u = (u + 0x7FFFu + ((u >> 16) & 1u)) >> 16;
    return (unsigned short)u;
}
__device__ __forceinline__ float bf2f(unsigned short h) {
    return __builtin_bit_cast(float, (unsigned)h << 16);
}

__device__ __forceinline__ void gll16(const void* g, void* l) {
    __builtin_amdgcn_global_load_lds((const __attribute__((address_space(1))) void*)g,
                                     (__attribute__((address_space(3))) void*)l, 16, 0, 0);
}

// ---------------------------------------------------------------------------
// Pack concat(x1,x2) -> padded NHWC bf16 xb[8][98][98][192], zero border.
// Extra grid row (yp==98): zero the border of vb (padded NHWC 96ch).
// NOTE: border zeroing must be exact — harness poisons buffers with 0xAA
// before timing; any unwritten-but-read cell fails replay validation.
__global__ __launch_bounds__(256) void pack_x_kernel(
    const float* __restrict__ x1, const float* __restrict__ x2,
    unsigned short* __restrict__ xb, unsigned short* __restrict__ vb)
{
    __shared__ unsigned short lds[192*100];
    const int tid = threadIdx.x;
    const int yp = blockIdx.x;      // 0..98
    const int b  = blockIdx.y;
    if (yp == 98) {                 // vb border zero for batch b
        unsigned short* vbb = vb + (size_t)b*PAD_*PAD_*96;
        for (int i = tid; i < 2*9408; i += 256) {   // rows 0 and 97 (full)
            int r = (i < 9408) ? 0 : 97;
            int o = (i < 9408) ? i : i - 9408;
            vbb[((size_t)r*PAD_)*96 + o] = 0;
        }
        for (int i = tid; i < 96*192; i += 256) {   // cols 0 and 97, rows 1..96
            int y = 1 + (i / 192);
            int rem = i % 192;
            int side = rem / 96;                    // 0 = col 0, 1 = col 97
            int c = rem % 96;
            vbb[((size_t)y*PAD_ + side*97)*96 + c] = 0;
        }
        return;
    }
    unsigned short* row = xb + ((size_t)(b*PAD_) + yp)*PAD_*192;
    if (yp == 0 || yp == PAD_-1) {
        for (int i = tid; i < PAD_*192; i += 256) row[i] = 0;
        return;
    }
    const int y = yp - 1;
    for (int i = tid; i < 2*HW_; i += 256) {
        const float* src = (i < HW_) ? x1 : x2;
        int ii = (i < HW_) ? i : i - HW_;
        int ch = ii / 96, x = ii - ch*96;
        int c = (i < HW_) ? ch : ch + 96;
        lds[c*100 + x] = f2bf(src[((size_t)(b*96 + ch))*HW_ + y*96 + x]);
    }
    __syncthreads();
    for (int i = tid; i < PAD_*192; i += 256) {
        int xp = i / 192, c = i - xp*192;
        row[i] = (xp == 0 || xp == PAD_-1) ? (unsigned short)0 : lds[c*100 + (xp-1)];
    }
}

// ---------------------------------------------------------------------------
// All 5 weight packs fused. fp32 [96][cin][3][3] -> bf16 fragment-linear:
// idx = (((step*6 + mf)*64 + lane)*8 + j), step = chunk*9 + tap,
// co = mf*16 + (lane&15), ci = chunk*32 + (lane>>4)*8 + j.
__global__ __launch_bounds__(256) void pack_w_all_kernel(
    const float* __restrict__ w1, const float* __restrict__ w2,
    const float* __restrict__ wa1, const float* __restrict__ wa2,
    const float* __restrict__ wa3,
    unsigned short* __restrict__ wf1, unsigned short* __restrict__ wf2,
    unsigned short* __restrict__ wfa1, unsigned short* __restrict__ wfa2,
    unsigned short* __restrict__ wfa3)
{
    int i = blockIdx.x*256 + threadIdx.x;   // < 663552
    const float* w; unsigned short* wf; int cin, rel;
    if      (i < 82944)  { w = w1;  wf = wf1;  cin = 96;  rel = i; }
    else if (i < 165888) { w = w2;  wf = wf2;  cin = 96;  rel = i - 82944; }
    else if (i < 331776) { w = wa1; wf = wfa1; cin = 192; rel = i - 165888; }
    else if (i < 497664) { w = wa2; wf = wfa2; cin = 192; rel = i - 331776; }
    else                 { w = wa3; wf = wfa3; cin = 192; rel = i - 497664; }
    int j = rel & 7;
    int lane = (rel >> 3) & 63;
    int blk = rel >> 9;
    int mf = blk % 6;
    int step = blk / 6;
    int chunk = step / 9, tap = step - chunk*9;
    int kh = tap / 3, kw = tap - kh*3;
    int m = lane & 15, g = lane >> 4;
    int co = mf*16 + m;
    int ci = chunk*32 + g*8 + j;
    wf[rel] = f2bf(w[(((size_t)co*cin + ci)*3 + kh)*3 + kw]);
}

// ---------------------------------------------------------------------------
// Fused implicit-GEMM 3x3 conv via MFMA, multi-job. blockIdx.z = which*8+b.
// 2-phase X staging (stage next -> compute -> one barrier). W operands are
// global->register with DEPTH-3 rotating prefetch: tap t issues the load for
// tap t+3 (~350cy lookahead > ~200-300cy L2 latency, the round-5 MfmaUtil=32%
// stall). Tap loop fully unrolled so wq[] indexing is compile-time (rule #20).
// MODE 1: bf16 NCHW out; 2: bf16 padded-NHWC out (96 ch).
struct ConvJobs {
    const unsigned short* xin[5];
    const unsigned short* wf[5];
    unsigned short* out[5];
    int chunks[5];
    int ci0[5];
    int mode[5];
    int wstride[5];
    int cistr[5];
};

__global__ __launch_bounds__(256, 2) void conv_mfma_kernel(ConvJobs j)
{
    __shared__ __align__(16) unsigned short xs[2][352*32];
    const int tid  = threadIdx.x;
    const int lane = tid & 63;
    const int wid  = tid >> 6;
    const int wm   = wid & 1;     // cout half (48)
    const int wp   = wid >> 1;    // pixel-row half (4 rows)
    const int x0 = blockIdx.x*32, y0 = blockIdx.y*8;
    const int which = blockIdx.z >> 3, b = blockIdx.z & 7;
    const int CHUNKS = j.chunks[which];
    const int CISTR  = j.cistr[which];
    const int ci0_base = j.ci0[which];
    const int NSTEP = CHUNKS*9;
    const unsigned short* xbb = j.xin[which] + (size_t)b*PAD_*PAD_*CISTR;
    const unsigned short* wfb = j.wf[which] + (size_t)b*j.wstride[which];

    auto stage = [&](int chunk, int buf) {
        int ci0 = ci0_base + chunk*32;
        for (int r = wid; r < 22; r += 4) {
            int gi = r*64 + lane;
            int pos = gi >> 2; if (pos > 339) pos = 339;
            int g = gi & 3;
            int gsrc = (g ^ pos) & 3;               // XOR granule swizzle
            int ty = pos / 34, tx = pos - ty*34;
            gll16(xbb + ((size_t)(y0 + ty)*PAD_ + (x0 + tx))*CISTR + ci0 + gsrc*8,
                  &xs[buf][r*512]);
        }
    };
    auto loadWd = [&](int step, short8* dst) {
        const unsigned short* wstep = wfb + (size_t)step*3072;
        dst[0] = *(const short8*)(wstep + ((wm*3+0)*64 + lane)*8);
        dst[1] = *(const short8*)(wstep + ((wm*3+1)*64 + lane)*8);
        dst[2] = *(const short8*)(wstep + ((wm*3+2)*64 + lane)*8);
    };

    f32x4 acc[3][8];
    f32x4 zero = {0.f, 0.f, 0.f, 0.f};
#pragma unroll
    for (int a = 0; a < 3; ++a)
#pragma unroll
        for (int f = 0; f < 8; ++f) acc[a][f] = zero;

    short8 wq[3][3];            // [depth slot][a] rotating W prefetch buffer
    loadWd(0, wq[0]);
    loadWd(1 < NSTEP ? 1 : 0, wq[1]);
    loadWd(2 < NSTEP ? 2 : 0, wq[2]);
    stage(0, 0);
    __syncthreads();

    for (int chunk = 0; chunk < CHUNKS; ++chunk) {
        const int cur = chunk & 1;
        if (chunk + 1 < CHUNKS) stage(chunk + 1, cur ^ 1);   // issue; fly under MFMAs
#pragma unroll
        for (int tap = 0; tap < 9; ++tap) {
            const int step = chunk*9 + tap;
            const int slot = tap % 3;                        // static after unroll
            short8 wa0 = wq[slot][0], wa1 = wq[slot][1], wa2 = wq[slot][2];
            int pf = step + 3; if (pf >= NSTEP) pf = NSTEP - 1;
            loadWd(pf, wq[slot]);                            // depth-3 prefetch
            const int kh = tap / 3, kw = tap - kh*3;
            const int n = lane & 15, gw = lane >> 4;
#pragma unroll
            for (int r = 0; r < 4; ++r) {
#pragma unroll
                for (int xh = 0; xh < 2; ++xh) {
                    int pos = (wp*4 + r + kh)*34 + (xh*16 + n + kw);
                    int g = (gw ^ pos) & 3;
                    short8 bfrag = *(const short8*)(&xs[cur][pos*32 + g*8]);
                    acc[0][r*2+xh] = __builtin_amdgcn_mfma_f32_16x16x32_bf16(wa0, bfrag, acc[0][r*2+xh], 0, 0, 0);
                    acc[1][r*2+xh] = __builtin_amdgcn_mfma_f32_16x16x32_bf16(wa1, bfrag, acc[1][r*2+xh], 0, 0, 0);
                    acc[2][r*2+xh] = __builtin_amdgcn_mfma_f32_16x16x32_bf16(wa2, bfrag, acc[2][r*2+xh], 0, 0, 0);
                }
            }
        }
        __syncthreads();   // drains stage(next); protects xs[cur] reuse
    }

    // epilogue: C/D layout col=lane&15 (pixel), row=(lane>>4)*4+reg (cout).
    int n = lane & 15, gw = lane >> 4;
    if (j.mode[which] == 1) {
        unsigned short* out = j.out[which];
#pragma unroll
        for (int a = 0; a < 3; ++a)
#pragma unroll
        for (int r = 0; r < 4; ++r)
#pragma unroll
        for (int xh = 0; xh < 2; ++xh) {
            int y = y0 + wp*4 + r, x = x0 + xh*16 + n;
#pragma unroll
            for (int reg = 0; reg < 4; ++reg) {
                int co = wm*48 + a*16 + gw*4 + reg;
                out[((size_t)(b*96 + co))*HW_ + y*96 + x] = f2bf(acc[a][r*2+xh][reg]);
            }
        }
    } else {
        unsigned short* out = j.out[which];  // padded NHWC, 96 ch
#pragma unroll
        for (int a = 0; a < 3; ++a)
#pragma unroll
        for (int r = 0; r < 4; ++r)
#pragma unroll
        for (int xh = 0; xh < 2; ++xh) {
            int y = y0 + wp*4 + r, x = x0 + xh*16 + n;
            int cb = wm*48 + a*16 + gw*4;
            f32x4 v = acc[a][r*2+xh];
            uint2 pv;
            pv.x = (unsigned)f2bf(v[0]) | ((unsigned)f2bf(v[1]) << 16);
            pv.y = (unsigned)f2bf(v[2]) | ((unsigned)f2bf(v[3]) << 16);
            *(uint2*)(out + ((size_t)(b*PAD_ + y+1)*PAD_ + (x+1))*96 + cb) = pv;
        }
    }
}

// ---------------------------------------------------------------------------
// Repack q,k NCHW bf16 -> tap-major [b][tap(9)][ch(96)][L=1024] via LDS.
__global__ __launch_bounds__(256) void repack_qk_kernel(
    const unsigned short* __restrict__ qb, const unsigned short* __restrict__ kb,
    unsigned short* __restrict__ qt, unsigned short* __restrict__ kt)
{
    __shared__ unsigned short q_lds[HW_], k_lds[HW_];
    const int tid = threadIdx.x;
    const int ch = blockIdx.x, b = blockIdx.y;
    const unsigned short* qsrc = qb + ((size_t)(b*96 + ch))*HW_;
    const unsigned short* ksrc = kb + ((size_t)(b*96 + ch))*HW_;
    for (int i = tid; i < HW_/8; i += 256) {
        *(short8*)(&q_lds[i*8]) = *(const short8*)(qsrc + i*8);
        *(short8*)(&k_lds[i*8]) = *(const short8*)(ksrc + i*8);
    }
    __syncthreads();
    const int l0 = tid*4;
    const int i0 = l0 >> 5, j0 = l0 & 31;
    for (int tap = 0; tap < 9; ++tap) {
        int kh = tap/3, kw = tap - kh*3;
        int base = (3*i0 + kh)*96 + kw;
        ushort4 vq, vk;
        vq.x = q_lds[base + 3*(j0+0)]; vq.y = q_lds[base + 3*(j0+1)];
        vq.z = q_lds[base + 3*(j0+2)]; vq.w = q_lds[base + 3*(j0+3)];
        vk.x = k_lds[base + 3*(j0+0)]; vk.y = k_lds[base + 3*(j0+1)];
        vk.z = k_lds[base + 3*(j0+2)]; vk.w = k_lds[base + 3*(j0+3)];
        size_t dst = (((size_t)(b*9 + tap))*96 + ch)*1024 + l0;
        *(ushort4*)(qt + dst) = vq;
        *(ushort4*)(kt + dst) = vk;
    }
}

// ---------------------------------------------------------------------------
// Gram partial: attnp[s][b][tap][cq][ck], L-split s in 0..3.
__global__ __launch_bounds__(256) void attn_mfma_kernel(
    const unsigned short* __restrict__ qt, const unsigned short* __restrict__ kt,
    float* __restrict__ attnp)
{
    __shared__ __align__(16) unsigned short qs[6144], ks[6144];
    const int tid = threadIdx.x, lane = tid & 63, wid = tid >> 6;
    const int tap = blockIdx.x, b = blockIdx.y, s = blockIdx.z;
    const int wm = wid & 1, wn = wid >> 1;
    const unsigned short* qbase = qt + ((size_t)(b*9 + tap))*96*1024;
    const unsigned short* kbase = kt + ((size_t)(b*9 + tap))*96*1024;

    f32x4 acc[3][3];
    f32x4 zero = {0.f, 0.f, 0.f, 0.f};
#pragma unroll
    for (int i = 0; i < 3; ++i)
#pragma unroll
        for (int j = 0; j < 3; ++j) acc[i][j] = zero;

    const int lrow = lane >> 3, lgr = lane & 7;
    for (int kc = 0; kc < 4; ++kc) {
        int L0 = s*256 + kc*64;
        for (int r = wid; r < 12; r += 4) {
            int row = r*8 + lrow;
            int gsrc = lgr ^ (row & 7);             // both-sides XOR swizzle
            gll16(qbase + (size_t)row*1024 + L0 + gsrc*8, &qs[r*512]);
        }
        for (int r = wid; r < 12; r += 4) {
            int row = r*8 + lrow;
            int gsrc = lgr ^ (row & 7);
            gll16(kbase + (size_t)row*1024 + L0 + gsrc*8, &ks[r*512]);
        }
        __syncthreads();
#pragma unroll
        for (int ks_ = 0; ks_ < 2; ++ks_) {
            short8 av[3], bv[3];
#pragma unroll
            for (int am = 0; am < 3; ++am) {
                int row = wm*48 + am*16 + (lane & 15);
                int gp = (ks_*4 + (lane >> 4)) ^ (row & 7);
                av[am] = *(const short8*)(&qs[row*64 + gp*8]);
            }
#pragma unroll
            for (int bn = 0; bn < 3; ++bn) {
                int row = wn*48 + bn*16 + (lane & 15);
                int gp = (ks_*4 + (lane >> 4)) ^ (row & 7);
                bv[bn] = *(const short8*)(&ks[row*64 + gp*8]);
            }
#pragma unroll
            for (int am = 0; am < 3; ++am)
#pragma unroll
                for (int bn = 0; bn < 3; ++bn)
                    acc[am][bn] = __builtin_amdgcn_mfma_f32_16x16x32_bf16(av[am], bv[bn], acc[am][bn], 0, 0, 0);
        }
        __syncthreads();
    }
    float* dst = attnp + ((((size_t)s*8 + b)*9 + tap))*9216;
#pragma unroll
    for (int am = 0; am < 3; ++am)
#pragma unroll
    for (int bn = 0; bn < 3; ++bn)
#pragma unroll
    for (int reg = 0; reg < 4; ++reg) {
        int cq = wm*48 + am*16 + (lane>>4)*4 + reg;
        int ck = wn*48 + bn*16 + (lane&15);
        dst[(size_t)cq*96 + ck] = acc[am][bn][reg];
    }
}

// ---------------------------------------------------------------------------
// softmax over m=(cq*9+tap); emits bf16 per-batch conv weights fragment-linear.
__global__ __launch_bounds__(256) void softmax_kernel(
    const float* __restrict__ attnp, unsigned short* __restrict__ wfab)
{
    __shared__ float red[256];
    const int tid = threadIdx.x;
    const int ck = blockIdx.x % 96, b = blockIdx.x / 96;
    const float scale = 0.03402069087198858f;   // 1/sqrt(864)
    float v[4];
#pragma unroll
    for (int r = 0; r < 4; ++r) {
        int m = r*256 + tid;
        if (m < 864) {
            int cq = m / 9, tap = m - cq*9;
            const float* ap = attnp + ((((size_t)b*9 + tap))*96 + cq)*96 + ck;
            v[r] = (ap[0] + ap[663552] + ap[2*663552] + ap[3*663552]) * scale;
        } else v[r] = -1e30f;
    }
    float mx = fmaxf(fmaxf(v[0], v[1]), fmaxf(v[2], v[3]));
    red[tid] = mx; __syncthreads();
    for (int s = 128; s > 0; s >>= 1) {
        if (tid < s) red[tid] = fmaxf(red[tid], red[tid+s]);
        __syncthreads();
    }
    mx = red[0]; __syncthreads();
    float e[4]; float lsum = 0.f;
#pragma unroll
    for (int r = 0; r < 4; ++r) {
        int m = r*256 + tid;
        if (m < 864) { e[r] = __expf(v[r] - mx); lsum += e[r]; }
        else e[r] = 0.f;
    }
    red[tid] = lsum; __syncthreads();
    for (int s = 128; s > 0; s >>= 1) {
        if (tid < s) red[tid] += red[tid+s];
        __syncthreads();
    }
    float inv = 1.f / red[0];
#pragma unroll
    for (int r = 0; r < 4; ++r) {
        int m = r*256 + tid;
        if (m < 864) {
            int cq = m / 9, tap = m - cq*9;
            int chunk = cq >> 5, cl = cq & 31, g = cl >> 3, j = cl & 7;
            int mf = ck >> 4, mrem = ck & 15;
            int lane2 = mrem + (g << 4);
            size_t oidx = (size_t)b*82944
                + ((((size_t)(chunk*9 + tap)*6 + mf)*64 + lane2)*8 + j);
            wfab[oidx] = f2bf(e[r]*inv);
        }
    }
}

// ---------------------------------------------------------------------------
__global__ __launch_bounds__(256) void bn_stats_kernel(
    const unsigned short* __restrict__ y1, const unsigned short* __restrict__ y2,
    const unsigned short* __restrict__ y3, float* __restrict__ stats)
{
    __shared__ float rs[256], rq[256];
    const int tid = threadIdx.x;
    const int t = blockIdx.x / 96, c = blockIdx.x % 96;
    const unsigned short* src = (t == 0) ? y1 : ((t == 1) ? y2 : y3);
    float s = 0.f, q2 = 0.f;
    for (int i = tid; i < 18432; i += 256) {
        int b = i / 2304, qd = i - b*2304;
        ushort4 v4 = *(const ushort4*)(src + ((size_t)(b*96 + c))*HW_ + qd*4);
        float f0 = bf2f(v4.x), f1 = bf2f(v4.y), f2v = bf2f(v4.z), f3 = bf2f(v4.w);
        s += f0+f1+f2v+f3; q2 += f0*f0+f1*f1+f2v*f2v+f3*f3;
    }
    rs[tid] = s; rq[tid] = q2; __syncthreads();
    for (int st = 128; st > 0; st >>= 1) {
        if (tid < st) { rs[tid] += rs[tid+st]; rq[tid] += rq[tid+st]; }
        __syncthreads();
    }
    if (tid == 0) {
        const float nn = 73728.f;
        float mu = rs[0] / nn;
        float var = rq[0] / nn - mu*mu;
        stats[blockIdx.x] = mu;
        stats[288 + blockIdx.x] = rsqrtf(var + 1e-5f);
    }
}

// ---------------------------------------------------------------------------
__global__ __launch_bounds__(256) void final_kernel(
    const float* __restrict__ x1, const float* __restrict__ x2,
    const unsigned short* __restrict__ y1, const unsigned short* __restrict__ y2,
    const unsigned short* __restrict__ y3, const float* __restrict__ stats,
    float* __restrict__ out)
{
    size_t q4 = (size_t)blockIdx.x*256 + threadIdx.x;  // quad id < 1769472
    size_t base = q4*4;
    int b  = (int)(base / CHW_);
    int c  = (int)((base / HW_) % 96);
    int hw = (int)(base % HW_);
    float mu1 = stats[c],       r1 = stats[288 + c];
    float mu2 = stats[96 + c],  r2 = stats[384 + c];
    float mu3 = stats[192 + c], r3 = stats[480 + c];
    float4 x1v = *(const float4*)(x1 + base);
    float4 x2v = *(const float4*)(x2 + base);
    ushort4 a1 = *(const ushort4*)(y1 + base);
    ushort4 a2 = *(const ushort4*)(y2 + base);
    ushort4 a3 = *(const ushort4*)(y3 + base);
    size_t lo = ((size_t)(b*192 + c))*HW_ + hw;
    size_t hi = lo + (size_t)96*HW_;
    float4 o0, o1;
    o0.x = x1v.x + ((bf2f(a1.x)-mu1)*r1) * ((bf2f(a2.x)-mu2)*r2);
    o0.y = x1v.y + ((bf2f(a1.y)-mu1)*r1) * ((bf2f(a2.y)-mu2)*r2);
    o0.z = x1v.z + ((bf2f(a1.z)-mu1)*r1) * ((bf2f(a2.z)-mu2)*r2);
    o0.w = x1v.w + ((bf2f(a1.w)-mu1)*r1) * ((bf2f(a2.w)-mu2)*r2);
    o1.x = x2v.x + (bf2f(a3.x)-mu3)*r3;
    o1.y = x2v.y + (bf2f(a3.y)-mu3)*r3;
    o1.z = x2v.z + (bf2f(a3.z)-mu3)*r3;
    o1.w = x2v.w + (bf2f(a3.w)-mu3)*r3;
    *(float4*)(out + lo) = o0;
    *(float4*)(out + hi) = o1;
    *(float4*)(out + OUTHALF_ + lo) = x1v;
    *(float4*)(out + OUTHALF_ + hi) = x2v;
}

// ---------------------------------------------------------------------------
extern "C" void kernel_launch(void* const* d_in, const int* in_sizes, int n_in,
                              void* d_out, int out_size, void* d_ws, size_t ws_size,
                              hipStream_t stream)
{
    const float* x1  = (const float*)d_in[0];
    const float* x2  = (const float*)d_in[1];
    const float* w1  = (const float*)d_in[2];
    const float* w2  = (const float*)d_in[3];
    const float* wa1 = (const float*)d_in[4];
    const float* wa2 = (const float*)d_in[5];
    const float* wa3 = (const float*)d_in[6];
    float* out = (float*)d_out;
    char* ws = (char*)d_ws;

    unsigned short* xb   = (unsigned short*)(ws);             // 29,503,488 B
    unsigned short* y1b  = (unsigned short*)(ws + 29503488);  // 14,155,776 B
    unsigned short* y2b  = (unsigned short*)(ws + 43659264);
    unsigned short* y3b  = (unsigned short*)(ws + 57815040);
    unsigned short* wf1  = (unsigned short*)(ws + 71970816);  // 165,888 B
    unsigned short* wf2  = (unsigned short*)(ws + 72136704);
    unsigned short* wfa1 = (unsigned short*)(ws + 72302592);  // 331,776 B
    unsigned short* wfa2 = (unsigned short*)(ws + 72634368);
    unsigned short* wfa3 = (unsigned short*)(ws + 72966144);
    unsigned short* wfab = (unsigned short*)(ws + 73297920);  // 1,327,104 B
    float* stats = (float*)(ws + 74625024);                   // 2,304 B

    // d_out scratch (all dead before final_kernel):
    unsigned short* qb    = (unsigned short*)out;                       // 14,155,776 B
    unsigned short* kkb   = (unsigned short*)((char*)out + 14155776);   // 14,155,776 B
    unsigned short* vb    = (unsigned short*)((char*)out + 28311552);   // 14,751,744 B
    unsigned short* qt    = (unsigned short*)((char*)out + 43063296);   // 14,155,776 B
    unsigned short* kt    = (unsigned short*)((char*)out + 57219072);   // 14,155,776 B
    float*          attnp = (float*)((char*)out + 71374848);            // 10,616,832 B

    pack_w_all_kernel<<<2592, 256, 0, stream>>>(w1, w2, wa1, wa2, wa3,
                                                wf1, wf2, wfa1, wfa2, wfa3);
    pack_x_kernel<<<dim3(99, 8), 256, 0, stream>>>(x1, x2, xb, vb);

    ConvJobs jA;
    jA.xin[0]=xb;  jA.wf[0]=wfa1; jA.out[0]=qb;  jA.chunks[0]=6; jA.ci0[0]=0;  jA.mode[0]=1; jA.wstride[0]=0; jA.cistr[0]=192;
    jA.xin[1]=xb;  jA.wf[1]=wfa2; jA.out[1]=kkb; jA.chunks[1]=6; jA.ci0[1]=0;  jA.mode[1]=1; jA.wstride[1]=0; jA.cistr[1]=192;
    jA.xin[2]=xb;  jA.wf[2]=wfa3; jA.out[2]=vb;  jA.chunks[2]=6; jA.ci0[2]=0;  jA.mode[2]=2; jA.wstride[2]=0; jA.cistr[2]=192;
    jA.xin[3]=xb;  jA.wf[3]=wf1;  jA.out[3]=y1b; jA.chunks[3]=3; jA.ci0[3]=0;  jA.mode[3]=1; jA.wstride[3]=0; jA.cistr[3]=192;
    jA.xin[4]=xb;  jA.wf[4]=wf2;  jA.out[4]=y2b; jA.chunks[4]=3; jA.ci0[4]=96; jA.mode[4]=1; jA.wstride[4]=0; jA.cistr[4]=192;
    conv_mfma_kernel<<<dim3(3, 12, 40), 256, 0, stream>>>(jA);

    repack_qk_kernel<<<dim3(96, 8), 256, 0, stream>>>(qb, kkb, qt, kt);
    attn_mfma_kernel<<<dim3(9, 8, 4), 256, 0, stream>>>(qt, kt, attnp);
    softmax_kernel<<<768, 256, 0, stream>>>(attnp, wfab);

    ConvJobs jB;
    for (int s = 0; s < 5; ++s) {
        jB.xin[s]=vb; jB.wf[s]=wfab; jB.out[s]=y3b; jB.chunks[s]=3; jB.ci0[s]=0;
        jB.mode[s]=1; jB.wstride[s]=82944; jB.cistr[s]=96;
    }
    conv_mfma_kernel<<<dim3(3, 12, 8), 256, 0, stream>>>(jB);

    bn_stats_kernel<<<288, 256, 0, stream>>>(y1b, y2b, y3b, stats);
    final_kernel<<<6912, 256, 0, stream>>>(x1, x2, y1b, y2b, y3b, stats, out);
}